// Round 5
// baseline (356.328 us; speedup 1.0000x reference)
//
#include <hip/hip_runtime.h>

#define NB 4
#define CIN 512
#define NPIX 4096
#define CQK 64
#define COUT 256
#define PPIX 4356   // 66*66 padded pixels

typedef __bf16 bh16;
typedef _Float16 fh16;
typedef __attribute__((ext_vector_type(8))) __bf16 bf16x8;
typedef __attribute__((ext_vector_type(8))) _Float16 f16x8;
typedef __attribute__((ext_vector_type(16))) float f32x16;

#define AS1 __attribute__((address_space(1)))
#define AS3 __attribute__((address_space(3)))

__device__ __forceinline__ void glds16(const void* g, void* l) {
  __builtin_amdgcn_global_load_lds((const AS1 unsigned int*)g, (AS3 unsigned int*)l, 16, 0, 0);
}

// LDS-only barrier: orders ds_write/ds_read across waves WITHOUT draining vmcnt.
__device__ __forceinline__ void lbar() {
  asm volatile("s_waitcnt lgkmcnt(0)\n\ts_barrier" ::: "memory");
}

// 2^x (Q is pre-scaled by log2e so attention needs exp2, not exp)
__device__ __forceinline__ float fexp2(float x) {
#if __has_builtin(__builtin_amdgcn_exp2f)
  return __builtin_amdgcn_exp2f(x);
#else
  return __expf(x * 0.6931471805599453f);
#endif
}

// ---------- transpose x [B][C][N] -> xTb [B][N][C] bf16 ----------
// 64x64 tile: float4 coalesced reads (256B/16-lane group), ushort4 writes (128B).
__global__ __launch_bounds__(256) void transpose_bf_k(const float* __restrict__ src,
                                                      bh16* __restrict__ dst) {
  __shared__ float tile[64][65];
  const int b = blockIdx.z;
  const int n0 = blockIdx.x * 64;   // N tile
  const int c0 = blockIdx.y * 64;   // C tile
  const float* s = src + (size_t)b * CIN * NPIX;
  bh16* d = dst + (size_t)b * CIN * NPIX;
  const int t = threadIdx.x;
  const int q4 = (t & 15) * 4;
  const int rr = t >> 4;
#pragma unroll
  for (int i = 0; i < 4; i++) {
    const int c = rr + i * 16;
    const float4 v = *(const float4*)&s[(size_t)(c0 + c) * NPIX + n0 + q4];
    tile[q4 + 0][c] = v.x;
    tile[q4 + 1][c] = v.y;
    tile[q4 + 2][c] = v.z;
    tile[q4 + 3][c] = v.w;
  }
  __syncthreads();
#pragma unroll
  for (int i = 0; i < 4; i++) {
    const int n = rr + i * 16;
    union { bh16 h[4]; ushort4 u; } pk;
    pk.h[0] = (bh16)tile[n][q4 + 0];
    pk.h[1] = (bh16)tile[n][q4 + 1];
    pk.h[2] = (bh16)tile[n][q4 + 2];
    pk.h[3] = (bh16)tile[n][q4 + 3];
    *(ushort4*)(void*)&d[(size_t)(n0 + n) * CIN + c0 + q4] = pk.u;
  }
}

// ---------- cast weights to bf16: Wqk[128][512] = [wq;wk], wvb[512][512], bias128 ----------
__global__ __launch_bounds__(256) void wcast_k(const float* __restrict__ wq,
                                               const float* __restrict__ wk,
                                               const float* __restrict__ wv,
                                               const float* __restrict__ bq,
                                               const float* __restrict__ bk,
                                               bh16* __restrict__ Wqk,
                                               bh16* __restrict__ wvb,
                                               float* __restrict__ bias128) {
  const int idx = blockIdx.x * 256 + threadIdx.x;
  if (idx < 65536) {
    Wqk[idx] = (bh16)(idx < 32768 ? wq[idx] : wk[idx - 32768]);
  } else {
    const int j = idx - 65536;
    wvb[j] = (bh16)wv[j];
  }
  if (idx < 128) bias128[idx] = idx < 64 ? bq[idx] : bk[idx - 64];
}

// ---------- Q|K projection via MFMA ----------
// Q half -> Qb [B*N][64] row-major, PRE-SCALED by log2(e); K half -> Kf fragment-swizzled:
// Kf[b][jtile64][kgrp8][j64][8]  (kgrp = k>>3, elem = k&7)
__global__ __launch_bounds__(256) void qk_proj_k(const bh16* __restrict__ xTb,
                                                 const bh16* __restrict__ Wqk,
                                                 const float* __restrict__ bias128,
                                                 bh16* __restrict__ Qb,
                                                 bh16* __restrict__ Kf) {
  const int blk = blockIdx.x;  // 256 blocks of 64 rows
  const int t = threadIdx.x;
  const int w = t >> 6, l31 = t & 31, hi = (t & 63) >> 5;
  __shared__ __align__(16) bh16 As[2][64 * 64];  // [row][slot*8] rotated
  f32x16 acc[2];
#pragma unroll
  for (int nt = 0; nt < 2; nt++)
#pragma unroll
    for (int r = 0; r < 16; r++) acc[nt][r] = 0.0f;

#define QK_STAGE(kc, buf)                                                           \
  {                                                                                 \
    _Pragma("unroll") for (int i = 0; i < 2; i++) {                                 \
      const int s = i * 256 + t;                                                    \
      const int n = s >> 3, slot = s & 7;                                           \
      glds16(xTb + (size_t)(blk * 64 + n) * CIN + (kc) * 64 + (((slot + n) & 7) * 8), \
             &As[buf][(size_t)(i * 256 + w * 64) * 8]);                             \
    }                                                                               \
  }

  QK_STAGE(0, 0);
  __syncthreads();
  for (int kc = 0; kc < 8; kc++) {
    if (kc < 7) QK_STAGE(kc + 1, (kc + 1) & 1);
    const bh16* as = As[kc & 1];
#pragma unroll
    for (int ks = 0; ks < 4; ks++) {
      const bf16x8 bfr = *(const bf16x8*)(Wqk + (size_t)(w * 32 + l31) * CIN + kc * 64 + ks * 16 + hi * 8);
      const int kk = ks * 2 + hi;
#pragma unroll
      for (int nt = 0; nt < 2; nt++) {
        const int n = nt * 32 + l31;
        const bf16x8 a = *(const bf16x8*)&as[(size_t)(n * 8 + ((kk - n) & 7)) * 8];
        acc[nt] = __builtin_amdgcn_mfma_f32_32x32x16_bf16(a, bfr, acc[nt], 0, 0, 0);
      }
    }
    __syncthreads();
  }
#undef QK_STAGE
  const int o = w * 32 + l31;
  const float bo = bias128[o];
  if (w < 2) {
    // Q half: Qb[row][o], scaled by log2(e) so attn can use v_exp_f32 (2^x) directly
#pragma unroll
    for (int nt = 0; nt < 2; nt++)
#pragma unroll
      for (int r = 0; r < 16; r++) {
        const int nloc = nt * 32 + (r & 3) + 8 * (r >> 2) + 4 * hi;
        Qb[(size_t)(blk * 64 + nloc) * 64 + o] = (bh16)((acc[nt][r] + bo) * 1.44269504088896f);
      }
  } else {
    // K half: Kf[b][jtile][kg][j][8]
    const int b = blk >> 6, jtile = blk & 63;
    const int k = o - 64, kg = k >> 3, k7 = k & 7;
    bh16* kdst = Kf + (((size_t)(b * 64 + jtile) * 8 + kg) * 64) * 8 + k7;
#pragma unroll
    for (int nt = 0; nt < 2; nt++)
#pragma unroll
      for (int r = 0; r < 16; r++) {
        const int j = nt * 32 + (r & 3) + 8 * (r >> 2) + 4 * hi;
        kdst[(size_t)j * 8] = (bh16)(acc[nt][r] + bo);
      }
  }
}

// ---------- V projection via MFMA, output fragment-swizzled ----------
// Vf[b][ntile64][kgrp8][c512][8]  (kgrp = (n&63)>>3, elem = n&7)
__global__ __launch_bounds__(256) void v_proj_k(const bh16* __restrict__ xTb,
                                                const bh16* __restrict__ wvb,
                                                const float* __restrict__ bv,
                                                bh16* __restrict__ Vf) {
  const int nblk = blockIdx.x;  // 16
  const int cblk = blockIdx.y;  // 8
  const int b = blockIdx.z;
  const int t = threadIdx.x;
  const int w = t >> 6, l31 = t & 31, hi = (t & 63) >> 5;
  __shared__ __align__(16) bh16 Bs[2][256 * 64];  // [row n][slot*8] rotated
  f32x16 acc[2][2];
#pragma unroll
  for (int mt = 0; mt < 2; mt++)
#pragma unroll
    for (int nt = 0; nt < 2; nt++)
#pragma unroll
      for (int r = 0; r < 16; r++) acc[mt][nt][r] = 0.0f;

#define V_STAGE(kc, buf)                                                              \
  {                                                                                   \
    _Pragma("unroll") for (int i = 0; i < 8; i++) {                                   \
      const int s = i * 256 + t;                                                      \
      const int n = s >> 3, slot = s & 7;                                             \
      glds16(xTb + (size_t)(b * NPIX + nblk * 256 + n) * CIN + (kc) * 64 + (((slot + n) & 7) * 8), \
             &Bs[buf][(size_t)(i * 256 + w * 64) * 8]);                               \
    }                                                                                 \
  }

  V_STAGE(0, 0);
  __syncthreads();
  for (int kc = 0; kc < 8; kc++) {
    if (kc < 7) V_STAGE(kc + 1, (kc + 1) & 1);
    const bh16* bs = Bs[kc & 1];
#pragma unroll
    for (int ks = 0; ks < 4; ks++) {
      const int kk = ks * 2 + hi;
      bf16x8 a[2], bfr[2];
#pragma unroll
      for (int mt = 0; mt < 2; mt++)
        a[mt] = *(const bf16x8*)(wvb + (size_t)(cblk * 64 + mt * 32 + l31) * CIN + kc * 64 + ks * 16 + hi * 8);
#pragma unroll
      for (int nt = 0; nt < 2; nt++) {
        const int n = w * 64 + nt * 32 + l31;
        bfr[nt] = *(const bf16x8*)&bs[(size_t)(n * 8 + ((kk - n) & 7)) * 8];
      }
#pragma unroll
      for (int mt = 0; mt < 2; mt++)
#pragma unroll
        for (int nt = 0; nt < 2; nt++)
          acc[mt][nt] = __builtin_amdgcn_mfma_f32_32x32x16_bf16(a[mt], bfr[nt], acc[mt][nt], 0, 0, 0);
    }
    __syncthreads();
  }
#undef V_STAGE
  const int ntile0 = nblk * 4 + w;
#pragma unroll
  for (int mt = 0; mt < 2; mt++)
#pragma unroll
    for (int r = 0; r < 16; r++) {
      const int c = cblk * 64 + mt * 32 + (r & 3) + 8 * (r >> 2) + 4 * hi;
      const float bvc = bv[c];
#pragma unroll
      for (int nt = 0; nt < 2; nt++) {
        const int nl = nt * 32 + l31;  // n within the 64-tile
        Vf[(((size_t)(b * 64 + ntile0) * 8 + (nl >> 3)) * 512 + c) * 8 + (nl & 7)] =
            (bh16)(acc[mt][nt][r] + bvc);
      }
    }
}

// ---------- single-pass attention (no-max softmax) + residual -> pa [B][N][C] f16 ----------
// BM=64, BN=256, XCD-aware remap. G2 is split across waves by (P-row-half mh2 = w&1,
// c-quarter cq = w>>1): each wave reads only HALF of P from LDS (4 b128/iter, not 8),
// trading a 2x V-fragment reload (L2-resident, cheap -- FETCH_SIZE 29MB proves V is
// cached) for a 2x cut in P LDS traffic, which round-3/4 showed dominates the loop.
// MFMA count unchanged (1 pf x 4 vf per ks); acc stays 4 x f32x16 = 64 regs.
// Ps layout is round-3's [jb][m][8] with single b128 reads (round-4's b64-split
// doubled LDS instruction count and regressed; its 2.1M conflicts are cheap).
// Round-1 lesson: NEVER unroll this loop or expand acc -- spills to scratch.
__global__ __launch_bounds__(256, 2) void attn1p_k(const bh16* __restrict__ Qb,
                                                   const bh16* __restrict__ Kf,
                                                   const bh16* __restrict__ Vf,
                                                   const float* __restrict__ x,
                                                   fh16* __restrict__ pa,
                                                   float* __restrict__ psum,
                                                   float* __restrict__ pmax) {
  // XCD-aware remap: id%8 selects (b,cblk); id/8 selects mblk.
  const int id = blockIdx.x + 2 * (blockIdx.y + 64 * blockIdx.z);
  const int b = (id & 7) >> 1;
  const int cblk = id & 1;
  const int mblk = (id >> 3) * 64;
  const int t = threadIdx.x;
  const int w = t >> 6, l31 = t & 31, hi = (t >> 5) & 1;
  const int jhalf = w & 1, mhalf = w >> 1;  // S-compute / P-write mapping
  const int mh2 = w & 1, cq = w >> 1;       // G2 mapping: P-row half, c-quarter
  __shared__ __align__(16) bh16 Ps[2][8 * 64 * 8];  // [buf][jb][m][8]  8KB each
  __shared__ float lred[4][32];
  __shared__ float linvL[64];
  __shared__ float cpool_s[4][4][32], cpool_m[4][4][32];

  // Q fragments (B-operand, col m = mhalf*32+l31), fixed for whole block
  bf16x8 qf[4];
  {
    const bh16* qrow = Qb + (size_t)(b * NPIX + mblk + mhalf * 32 + l31) * 64;
#pragma unroll
    for (int ks = 0; ks < 4; ks++) qf[ks] = *(const bf16x8*)(qrow + ks * 16 + hi * 8);
  }
  const bh16* kfb = Kf + (size_t)b * (64 * 8 * 64 * 8);
  const bh16* vfb = Vf + (size_t)b * (64 * 8 * 512 * 8);
  const int cbase = cblk * 256 + cq * 128;  // this wave's 128-channel slice

#define KADDR(tile, ks) (kfb + (((size_t)(tile) * 8 + (ks) * 2 + hi) * 64 + jhalf * 32 + l31) * 8)
#define VADDR(tile, ks, ct) (vfb + (((size_t)(tile) * 8 + (ks) * 2 + hi) * 512 + cbase + (ct) * 32 + l31) * 8)

  f32x16 acc[4];  // [ct]: rows = m (mh2 half, reg-mapped), cols = cbase+ct*32+l31
#pragma unroll
  for (int ct = 0; ct < 4; ct++)
#pragma unroll
    for (int r = 0; r < 16; r++) acc[ct][r] = 0.0f;
  float4 lsacc;
  lsacc.x = 0.0f; lsacc.y = 0.0f; lsacc.z = 0.0f; lsacc.w = 0.0f;

  // pipeline registers (single-buffered, reload-after-last-use)
  bf16x8 kf_nxt[4];       // K(it+1) at top of iter it
  bf16x8 vf_use[4][4];    // V(it-1) at top of iter it (4 ks x 4 ct)
  f32x16 s1;              // raw S(it)
  {
    bf16x8 k0[4];
#pragma unroll
    for (int ks = 0; ks < 4; ks++) {
      k0[ks] = *(const bf16x8*)KADDR(0, ks);
#pragma unroll
      for (int ct = 0; ct < 4; ct++) vf_use[ks][ct] = *(const bf16x8*)VADDR(0, ks, ct);
    }
#pragma unroll
    for (int ks = 0; ks < 4; ks++) kf_nxt[ks] = *(const bf16x8*)KADDR(1, ks);
#pragma unroll
    for (int r = 0; r < 16; r++) s1[r] = 0.0f;
#pragma unroll
    for (int ks = 0; ks < 4; ks++)
      s1 = __builtin_amdgcn_mfma_f32_32x32x16_bf16(k0[ks], qf[ks], s1, 0, 0, 0);
  }

  for (int it = 0; it < 64; it++) {
    // G1 for it+1 (result for next iteration; garbage at it=63, unused)
    f32x16 s1n;
#pragma unroll
    for (int r = 0; r < 16; r++) s1n[r] = 0.0f;
#pragma unroll
    for (int ks = 0; ks < 4; ks++)
      s1n = __builtin_amdgcn_mfma_f32_32x32x16_bf16(kf_nxt[ks], qf[ks], s1n, 0, 0, 0);
    // kf_nxt dead now -> reload K(it+2) immediately (cover = rest of body + barrier)
    {
      const int kt = (it + 2 < 64) ? it + 2 : 63;
#pragma unroll
      for (int ks = 0; ks < 4; ks++) kf_nxt[ks] = *(const bf16x8*)KADDR(kt, ks);
    }

    const bh16* ps = Ps[(it + 1) & 1];  // == (it-1)&1
    bh16* psw = Ps[it & 1];
    if (it) {
      // G2(it-1) [MFMA] interleaved with exp/pack(it) [VALU] -- independent
#pragma unroll
      for (int ks = 0; ks < 4; ks++) {
        const int ks2 = ks * 2 + hi;
        // only this wave's m-half of P: 4 b128 reads/iter instead of 8
        const bf16x8 pf = *(const bf16x8*)&ps[(size_t)(ks2 * 64 + mh2 * 32 + l31) * 8];
        acc[0] = __builtin_amdgcn_mfma_f32_32x32x16_bf16(pf, vf_use[ks][0], acc[0], 0, 0, 0);
        acc[1] = __builtin_amdgcn_mfma_f32_32x32x16_bf16(pf, vf_use[ks][1], acc[1], 0, 0, 0);
        // one exp/pack group between MFMA clusters
        {
          union { bh16 h[4]; uint2 u2; } pk;
#pragma unroll
          for (int q = 0; q < 4; q++) {
            const float p = fexp2(s1[ks * 4 + q]);
            lsacc[q] += p;
            pk.h[q] = (bh16)p;
          }
          *(uint2*)(void*)&psw[(size_t)((jhalf * 4 + ks) * 64 + mhalf * 32 + l31) * 8 + hi * 4] = pk.u2;
        }
        acc[2] = __builtin_amdgcn_mfma_f32_32x32x16_bf16(pf, vf_use[ks][2], acc[2], 0, 0, 0);
        acc[3] = __builtin_amdgcn_mfma_f32_32x32x16_bf16(pf, vf_use[ks][3], acc[3], 0, 0, 0);
        // vf_use[ks] dead now -> reload V(it) for next iteration's G2 (~1-iter cover)
#pragma unroll
        for (int ct = 0; ct < 4; ct++) vf_use[ks][ct] = *(const bf16x8*)VADDR(it, ks, ct);
      }
    } else {
#pragma unroll
      for (int g = 0; g < 4; g++) {
        union { bh16 h[4]; uint2 u2; } pk;
#pragma unroll
        for (int q = 0; q < 4; q++) {
          const float p = fexp2(s1[g * 4 + q]);
          lsacc[q] += p;
          pk.h[q] = (bh16)p;
        }
        *(uint2*)(void*)&psw[(size_t)((jhalf * 4 + g) * 64 + mhalf * 32 + l31) * 8 + hi * 4] = pk.u2;
      }
      // vf_use keeps prologue-loaded V(0) for iter 1's G2
    }
    lbar();  // P(it) visible; K/V global loads stay in flight across the barrier
    s1 = s1n;
  }
  // final G2: P(63) x V(63)
  {
    const bh16* ps = Ps[1];
#pragma unroll
    for (int ks = 0; ks < 4; ks++) {
      const int ks2 = ks * 2 + hi;
      const bf16x8 pf = *(const bf16x8*)&ps[(size_t)(ks2 * 64 + mh2 * 32 + l31) * 8];
#pragma unroll
      for (int ct = 0; ct < 4; ct++)
        acc[ct] = __builtin_amdgcn_mfma_f32_32x32x16_bf16(pf, vf_use[ks][ct], acc[ct], 0, 0, 0);
    }
  }
#undef KADDR
#undef VADDR

  // reduce row-sums: lanes (hi) within wave, then across jhalf wave pairs
  float lsum = (lsacc.x + lsacc.y) + (lsacc.z + lsacc.w);
  lsum += __shfl_xor(lsum, 32);
  if (hi == 0) lred[w][l31] = lsum;
  __syncthreads();
  if (t < 64) linvL[t] = 1.0f / (lred[(t >> 5) * 2][t & 31] + lred[(t >> 5) * 2 + 1][t & 31]);
  __syncthreads();

  // epilogue: normalize + residual, write pa[B][N][C] f16 + pooling partials.
  // This wave covers m in [mh2*32, mh2*32+32) x c in [cbase, cbase+128).
  float csum[4] = {0.0f, 0.0f, 0.0f, 0.0f};
  float cmax[4] = {-1e30f, -1e30f, -1e30f, -1e30f};
#pragma unroll
  for (int g = 0; g < 4; g++) {
    const int mloc = mh2 * 32 + g * 8 + hi * 4;
    const float4 lv = *(const float4*)&linvL[mloc];
#pragma unroll
    for (int ct = 0; ct < 4; ct++) {
      const int c = cbase + ct * 32 + l31;
      const float4 xv = *(const float4*)&x[(size_t)(b * CIN + c) * NPIX + mblk + mloc];
      float r0 = acc[ct][g * 4 + 0] * lv.x + xv.x;
      float r1 = acc[ct][g * 4 + 1] * lv.y + xv.y;
      float r2 = acc[ct][g * 4 + 2] * lv.z + xv.z;
      float r3 = acc[ct][g * 4 + 3] * lv.w + xv.w;
      csum[ct] += (r0 + r1) + (r2 + r3);
      cmax[ct] = fmaxf(cmax[ct], fmaxf(fmaxf(r0, r1), fmaxf(r2, r3)));
      fh16* pd = pa + ((size_t)(b * NPIX) + mblk + mloc) * CIN + c;
      pd[0 * CIN] = (fh16)r0;
      pd[1 * CIN] = (fh16)r1;
      pd[2 * CIN] = (fh16)r2;
      pd[3 * CIN] = (fh16)r3;
    }
  }
  // combine hi halves (same c, disjoint m-subsets within the wave's 32 m)
#pragma unroll
  for (int ct = 0; ct < 4; ct++) {
    csum[ct] += __shfl_xor(csum[ct], 32);
    cmax[ct] = fmaxf(cmax[ct], __shfl_xor(cmax[ct], 32));
  }
  if (hi == 0) {
#pragma unroll
    for (int ct = 0; ct < 4; ct++) {
      cpool_s[w][ct][l31] = csum[ct];
      cpool_m[w][ct][l31] = cmax[ct];
    }
  }
  __syncthreads();
  // waves (0,1) share cq=0, (2,3) share cq=1 with complementary m-halves: combine pairs
  if ((w & 1) == 0 && hi == 0) {
    const int mb = mblk >> 6;
#pragma unroll
    for (int ct = 0; ct < 4; ct++) {
      const int c = cbase + ct * 32 + l31;
      psum[((size_t)b * 64 + mb) * CIN + c] = cpool_s[w][ct][l31] + cpool_s[w + 1][ct][l31];
      pmax[((size_t)b * 64 + mb) * CIN + c] = fmaxf(cpool_m[w][ct][l31], cpool_m[w + 1][ct][l31]);
    }
  }
}

// ---------- channel-attention MLP (with fused partial-pool reduce) -> sigmoid scale ----------
__global__ __launch_bounds__(256) void mlp2_k(const float* __restrict__ psum,
                                              const float* __restrict__ pmax,
                                              const float* __restrict__ w1,
                                              const float* __restrict__ w2,
                                              float* __restrict__ scale) {
  const int b = blockIdx.x;
  const int t = threadIdx.x;
  __shared__ float avg_l[CIN], max_l[CIN], hbuf[128];
#pragma unroll
  for (int h = 0; h < 2; h++) {
    const int c = t + h * 256;
    float s = 0.0f, m = -1e30f;
#pragma unroll
    for (int k = 0; k < 64; k++) {
      s += psum[((size_t)b * 64 + k) * CIN + c];
      m = fmaxf(m, pmax[((size_t)b * 64 + k) * CIN + c]);
    }
    avg_l[c] = s * (1.0f / 4096.0f);
    max_l[c] = m;
  }
  __syncthreads();
  if (t < 128) {
    const float* src = (t < 64) ? avg_l : max_l;
    const int o = t & 63;
    float sacc = 0.0f;
    for (int c = 0; c < CIN; c += 4) {
      const float4 wv = *(const float4*)&w1[o * CIN + c];
      sacc += wv.x * src[c] + wv.y * src[c + 1] + wv.z * src[c + 2] + wv.w * src[c + 3];
    }
    hbuf[t] = fmaxf(sacc, 0.0f);
  }
  __syncthreads();
#pragma unroll
  for (int h = 0; h < 2; h++) {
    const int c = t + h * 256;
    float sacc = 0.0f;
#pragma unroll
    for (int k = 0; k < 64; k += 4) {
      const float4 wv = *(const float4*)&w2[c * 64 + k];
      sacc += wv.x * (hbuf[k] + hbuf[64 + k]) + wv.y * (hbuf[k + 1] + hbuf[64 + k + 1]) +
              wv.z * (hbuf[k + 2] + hbuf[64 + k + 2]) + wv.w * (hbuf[k + 3] + hbuf[64 + k + 3]);
    }
    scale[b * CIN + c] = 1.0f / (1.0f + __expf(-sacc));
  }
}

// ---------- pack pa[B][N][C] f16 * scale -> f16 padded pixel-major [B][66*66][512] ----------
// Same inner (channel) layout on both sides: pure coalesced row copy with per-ch scale.
__global__ __launch_bounds__(256) void pack_k(const fh16* __restrict__ pa,
                                              const float* __restrict__ scl,
                                              fh16* __restrict__ pab) {
  const int b = blockIdx.y;
  const int n0 = blockIdx.x * 8;
  const int t = threadIdx.x;
  __shared__ float sc[CIN];
#pragma unroll
  for (int h = 0; h < 2; h++) sc[t + h * 256] = scl[b * CIN + t + h * 256];
  __syncthreads();
  const int c2 = t * 2;
  const float s0 = sc[c2], s1 = sc[c2 + 1];
#pragma unroll
  for (int j = 0; j < 8; j++) {
    const int n = n0 + j;
    const int pp = ((n >> 6) + 1) * 66 + (n & 63) + 1;
    union { fh16 h[2]; unsigned int u; } v, o;
    v.u = *(const unsigned int*)(pa + ((size_t)b * NPIX + n) * CIN + c2);
    o.h[0] = (fh16)((float)v.h[0] * s0);
    o.h[1] = (fh16)((float)v.h[1] * s1);
    *(unsigned int*)(void*)(pab + ((size_t)b * PPIX + pp) * CIN + c2) = o.u;
  }
}

// ---------- zero the SAME-padding borders of pab (interior written by pack_k) ----------
// 260 border pixels per image: row0 (66), row65 (66), col0 rows1-64 (64), col65 rows1-64 (64)
__global__ __launch_bounds__(256) void bzero_k(fh16* __restrict__ pab) {
  const int t = threadIdx.x;
  const int p = blockIdx.x * 4 + (t >> 6);  // 0..259
  const int b = blockIdx.y;
  int pp;
  if (p < 66) pp = p;
  else if (p < 132) pp = 65 * 66 + (p - 66);
  else if (p < 196) pp = (p - 131) * 66;
  else pp = (p - 195) * 66 + 65;
  uint4 z = {0u, 0u, 0u, 0u};
  *(uint4*)(void*)(pab + ((size_t)b * PPIX + pp) * CIN + (t & 63) * 8) = z;
}

// ---------- repack conv weights -> f16 [oblk4][chunk32][tap9][chalf2][o64][8] ----------
// chalf-major over o gives the conv kernel 16B-lane-stride LDS reads (no 2x bank waste)
__global__ __launch_bounds__(256) void wpack_k(const float* __restrict__ cw,
                                               fh16* __restrict__ wp) {
  const int slot = blockIdx.x * 256 + threadIdx.x;  // one 8-f16 group
  const int oblk = slot / 36864;
  const int r1 = slot - oblk * 36864;
  const int chunk = r1 / 1152;
  const int r2 = r1 - chunk * 1152;
  const int tap = r2 >> 7;
  const int r3 = r2 & 127;
  const int h = r3 >> 6;
  const int o = r3 & 63;
  const size_t sbase = (size_t)(oblk * 64 + o) * 4608 + (size_t)(chunk * 16 + h * 8) * 9 + tap;
  union { fh16 h8[8]; uint4 u4; } pk;
#pragma unroll
  for (int i = 0; i < 8; i++) pk.h8[i] = (fh16)cw[sbase + (size_t)i * 9];
  *(uint4*)(void*)(wp + (size_t)slot * 8) = pk.u4;
}

// ---------- implicit-GEMM 3x3 conv via f16 MFMA + BN + ReLU ----------
// Xs layout [batch13][chalf2][row32][8], Ws layout [tap9][chalf2][o64][8]:
// all ds_read_b128 at 16B lane stride (full 32-bank sweep) instead of 32B (half banks).
__global__ __launch_bounds__(256) void conv_mfma_k(const fh16* __restrict__ pab,
                                                   const fh16* __restrict__ wp,
                                                   const float* __restrict__ gamma,
                                                   const float* __restrict__ beta,
                                                   const float* __restrict__ mean,
                                                   const float* __restrict__ var,
                                                   float* __restrict__ out) {
  const int y0 = blockIdx.x * 4;
  const int oblk = blockIdx.y;
  const int b = blockIdx.z;
  const int t = threadIdx.x;
  const int w = t >> 6, lane = t & 63, l31 = lane & 31, hi = lane >> 5;
  __shared__ __align__(16) fh16 Xs[2][416 * 16];
  __shared__ __align__(16) fh16 Ws[2][9 * 64 * 16];
  __shared__ float sb[64], bb[64];
  if (t < 64) {
    const int o = oblk * 64 + t;
    const float inv = rsqrtf(var[o] + 1e-5f);
    const float sc = inv * gamma[o];
    sb[t] = sc;
    bb[t] = beta[o] - mean[o] * sc;
  }
  f32x16 o00, o01, o10, o11;
#pragma unroll
  for (int r = 0; r < 16; r++) { o00[r] = 0.0f; o01[r] = 0.0f; o10[r] = 0.0f; o11[r] = 0.0f; }

  // lane -> (row-in-batch = lane&31, chalf = lane>>5): LDS dest is linear, so the
  // [batch][chalf][row][8] layout is created purely by the per-lane GLOBAL address.
  const fh16* xbase = pab + ((size_t)b * PPIX + y0 * 66) * CIN + (size_t)(lane & 31) * CIN + (lane >> 5) * 8;
  const fh16* wbase = wp + (size_t)oblk * 32 * 9216 + lane * 8;

#define STAGE(chunk, buf)                                                        \
  {                                                                              \
    const fh16* xs = xbase + (chunk) * 16;                                       \
    for (int i = w; i < 13; i += 4)                                              \
      glds16(xs + (size_t)i * 32 * CIN, &Xs[buf][i * 512]);                      \
    const fh16* wsrc = wbase + (size_t)(chunk) * 9216;                           \
    for (int i = w; i < 18; i += 4)                                              \
      glds16(wsrc + (size_t)i * 512, &Ws[buf][i * 512]);                         \
  }

  STAGE(0, 0);
  __syncthreads();
  for (int chunk = 0; chunk < 32; chunk++) {
    if (chunk < 31) STAGE(chunk + 1, (chunk + 1) & 1);
    const fh16* xs = Xs[chunk & 1];
    const fh16* ws = Ws[chunk & 1];
#pragma unroll
    for (int tap = 0; tap < 9; tap++) {
      const int ky = tap / 3, kx = tap - ky * 3;
      const f16x8 a0 = *(const f16x8*)&ws[tap * 1024 + hi * 512 + l31 * 8];
      const f16x8 a1 = *(const f16x8*)&ws[tap * 1024 + hi * 512 + (32 + l31) * 8];
      const int row0 = (w + ky) * 66 + l31 + kx;
      const int row1 = row0 + 32;
      const f16x8 b0 = *(const f16x8*)&xs[(row0 >> 5) * 512 + hi * 256 + (row0 & 31) * 8];
      const f16x8 b1 = *(const f16x8*)&xs[(row1 >> 5) * 512 + hi * 256 + (row1 & 31) * 8];
      o00 = __builtin_amdgcn_mfma_f32_32x32x16_f16(a0, b0, o00, 0, 0, 0);
      o01 = __builtin_amdgcn_mfma_f32_32x32x16_f16(a0, b1, o01, 0, 0, 0);
      o10 = __builtin_amdgcn_mfma_f32_32x32x16_f16(a1, b0, o10, 0, 0, 0);
      o11 = __builtin_amdgcn_mfma_f32_32x32x16_f16(a1, b1, o11, 0, 0, 0);
    }
    __syncthreads();
  }
#undef STAGE

  const f32x16* accs[2][2] = {{&o00, &o01}, {&o10, &o11}};
#pragma unroll
  for (int mt = 0; mt < 2; mt++) {
#pragma unroll
    for (int nt = 0; nt < 2; nt++) {
      const f32x16& A = *accs[mt][nt];
#pragma unroll
      for (int r = 0; r < 16; r++) {
        const int cl = mt * 32 + (r & 3) + 8 * (r >> 2) + 4 * hi;
        const int pix = nt * 32 + l31;
        const float y = A[r] * sb[cl] + bb[cl];
        out[((size_t)(b * COUT + oblk * 64 + cl)) * NPIX + (y0 + w) * 64 + pix] = fmaxf(y, 0.0f);
      }
    }
  }
}

extern "C" void kernel_launch(void* const* d_in, const int* in_sizes, int n_in,
                              void* d_out, int out_size, void* d_ws, size_t ws_size,
                              hipStream_t stream) {
  (void)in_sizes; (void)n_in; (void)out_size; (void)ws_size;
  const float* x        = (const float*)d_in[0];
  const float* wq       = (const float*)d_in[1];
  const float* bq       = (const float*)d_in[2];
  const float* wk       = (const float*)d_in[3];
  const float* bk       = (const float*)d_in[4];
  const float* wv       = (const float*)d_in[5];
  const float* bv       = (const float*)d_in[6];
  const float* ca_w1    = (const float*)d_in[7];
  const float* ca_w2    = (const float*)d_in[8];
  const float* conv_w   = (const float*)d_in[9];
  const float* bn_gamma = (const float*)d_in[10];
  const float* bn_beta  = (const float*)d_in[11];
  const float* bn_mean  = (const float*)d_in[12];
  const float* bn_var   = (const float*)d_in[13];
  float* out = (float*)d_out;

  float* ws = (float*)d_ws;
  fh16*  pa      = (fh16*)ws;                   // [B][N][C] f16 (16.8 MB)
  float* psum    = ws + 4194304;                // [B][64][C] fp32 partial sums (512 KB)
  float* pmax    = ws + 4325376;                // [B][64][C] fp32 partial maxes (512 KB)
  bh16*  Vf      = (bh16*)(ws + 8388608);       // [B][64][8][512][8] bf16 (aliased by wpck later)
  fh16*  wpck    = (fh16*)(ws + 8388608);       // conv weights f16 (after attn)
  bh16*  Qb      = (bh16*)(ws + 12582912);      // [B*N][64] bf16
  bh16*  Kf      = (bh16*)(ws + 13107200);      // [B][64][8][64][8] bf16
  bh16*  xTb     = (bh16*)(ws + 13631488);      // [B][N][C] bf16 (aliased by pab later)
  fh16*  pab     = (fh16*)(ws + 13631488);      // [B][4356][512] f16 + pad
  bh16*  Wqk     = (bh16*)(ws + 17825792);      // [128][512] bf16
  bh16*  wvb     = (bh16*)(ws + 17858560);      // [512][512] bf16
  float* bias128 = ws + 17989632;
  float* scl     = ws + 18104320;

  wcast_k<<<dim3(1280, 1, 1), 256, 0, stream>>>(wq, wk, wv, bq, bk, Wqk, wvb, bias128);
  transpose_bf_k<<<dim3(NPIX / 64, CIN / 64, NB), 256, 0, stream>>>(x, xTb);
  qk_proj_k<<<dim3(256, 1, 1), 256, 0, stream>>>(xTb, Wqk, bias128, Qb, Kf);
  v_proj_k<<<dim3(16, 8, NB), 256, 0, stream>>>(xTb, wvb, bv, Vf);
  attn1p_k<<<dim3(2, 64, NB), 256, 0, stream>>>(Qb, Kf, Vf, x, pa, psum, pmax);
  // xTb dead now: zero only the conv SAME-padding borders (pack_k writes all interior;
  // staging over-reads past pab land in allocated pad and are never consumed)
  bzero_k<<<dim3(65, NB, 1), 256, 0, stream>>>(pab);
  mlp2_k<<<dim3(NB, 1, 1), 256, 0, stream>>>(psum, pmax, ca_w1, ca_w2, scl);
  pack_k<<<dim3(NPIX / 8, NB, 1), 256, 0, stream>>>(pa, scl, pab);
  wpack_k<<<dim3(576, 1, 1), 256, 0, stream>>>(conv_w, wpck);  // Vf dead now
  conv_mfma_k<<<dim3(16, 4, NB), 256, 0, stream>>>(pab, wpck, bn_gamma, bn_beta,
                                                   bn_mean, bn_var, out);
}

// Round 6
// 328.696 us; speedup vs baseline: 1.0841x; 1.0841x over previous
//
#include <hip/hip_runtime.h>

#define NB 4
#define CIN 512
#define NPIX 4096
#define CQK 64
#define COUT 256
#define PPIX 4356   // 66*66 padded pixels

typedef __bf16 bh16;
typedef _Float16 fh16;
typedef __attribute__((ext_vector_type(8))) __bf16 bf16x8;
typedef __attribute__((ext_vector_type(8))) _Float16 f16x8;
typedef __attribute__((ext_vector_type(16))) float f32x16;

#define AS1 __attribute__((address_space(1)))
#define AS3 __attribute__((address_space(3)))

__device__ __forceinline__ void glds16(const void* g, void* l) {
  __builtin_amdgcn_global_load_lds((const AS1 unsigned int*)g, (AS3 unsigned int*)l, 16, 0, 0);
}

// 2^x (Q is pre-scaled by log2e so attention needs exp2, not exp)
__device__ __forceinline__ float fexp2(float x) {
#if __has_builtin(__builtin_amdgcn_exp2f)
  return __builtin_amdgcn_exp2f(x);
#else
  return __expf(x * 0.6931471805599453f);
#endif
}

// ---------- transpose x [B][C][N] -> xTb [B][N][C] bf16 ----------
// 64x64 tile: float4 coalesced reads (256B/16-lane group), ushort4 writes (128B).
__global__ __launch_bounds__(256) void transpose_bf_k(const float* __restrict__ src,
                                                      bh16* __restrict__ dst) {
  __shared__ float tile[64][65];
  const int b = blockIdx.z;
  const int n0 = blockIdx.x * 64;   // N tile
  const int c0 = blockIdx.y * 64;   // C tile
  const float* s = src + (size_t)b * CIN * NPIX;
  bh16* d = dst + (size_t)b * CIN * NPIX;
  const int t = threadIdx.x;
  const int q4 = (t & 15) * 4;
  const int rr = t >> 4;
#pragma unroll
  for (int i = 0; i < 4; i++) {
    const int c = rr + i * 16;
    const float4 v = *(const float4*)&s[(size_t)(c0 + c) * NPIX + n0 + q4];
    tile[q4 + 0][c] = v.x;
    tile[q4 + 1][c] = v.y;
    tile[q4 + 2][c] = v.z;
    tile[q4 + 3][c] = v.w;
  }
  __syncthreads();
#pragma unroll
  for (int i = 0; i < 4; i++) {
    const int n = rr + i * 16;
    union { bh16 h[4]; ushort4 u; } pk;
    pk.h[0] = (bh16)tile[n][q4 + 0];
    pk.h[1] = (bh16)tile[n][q4 + 1];
    pk.h[2] = (bh16)tile[n][q4 + 2];
    pk.h[3] = (bh16)tile[n][q4 + 3];
    *(ushort4*)(void*)&d[(size_t)(n0 + n) * CIN + c0 + q4] = pk.u;
  }
}

// ---------- cast weights to bf16: Wqk[128][512] = [wq;wk], wvb[512][512], bias128 ----------
__global__ __launch_bounds__(256) void wcast_k(const float* __restrict__ wq,
                                               const float* __restrict__ wk,
                                               const float* __restrict__ wv,
                                               const float* __restrict__ bq,
                                               const float* __restrict__ bk,
                                               bh16* __restrict__ Wqk,
                                               bh16* __restrict__ wvb,
                                               float* __restrict__ bias128) {
  const int idx = blockIdx.x * 256 + threadIdx.x;
  if (idx < 65536) {
    Wqk[idx] = (bh16)(idx < 32768 ? wq[idx] : wk[idx - 32768]);
  } else {
    const int j = idx - 65536;
    wvb[j] = (bh16)wv[j];
  }
  if (idx < 128) bias128[idx] = idx < 64 ? bq[idx] : bk[idx - 64];
}

// ---------- Q|K projection via MFMA ----------
// Q half -> Qb [B*N][64] row-major, PRE-SCALED by log2(e); K half -> Kf fragment-swizzled:
// Kf[b][jtile64][kgrp8][j64][8]  (kgrp = k>>3, elem = k&7)
__global__ __launch_bounds__(256) void qk_proj_k(const bh16* __restrict__ xTb,
                                                 const bh16* __restrict__ Wqk,
                                                 const float* __restrict__ bias128,
                                                 bh16* __restrict__ Qb,
                                                 bh16* __restrict__ Kf) {
  const int blk = blockIdx.x;  // 256 blocks of 64 rows
  const int t = threadIdx.x;
  const int w = t >> 6, l31 = t & 31, hi = (t & 63) >> 5;
  __shared__ __align__(16) bh16 As[2][64 * 64];  // [row][slot*8] rotated
  f32x16 acc[2];
#pragma unroll
  for (int nt = 0; nt < 2; nt++)
#pragma unroll
    for (int r = 0; r < 16; r++) acc[nt][r] = 0.0f;

#define QK_STAGE(kc, buf)                                                           \
  {                                                                                 \
    _Pragma("unroll") for (int i = 0; i < 2; i++) {                                 \
      const int s = i * 256 + t;                                                    \
      const int n = s >> 3, slot = s & 7;                                           \
      glds16(xTb + (size_t)(blk * 64 + n) * CIN + (kc) * 64 + (((slot + n) & 7) * 8), \
             &As[buf][(size_t)(i * 256 + w * 64) * 8]);                             \
    }                                                                               \
  }

  QK_STAGE(0, 0);
  __syncthreads();
  for (int kc = 0; kc < 8; kc++) {
    if (kc < 7) QK_STAGE(kc + 1, (kc + 1) & 1);
    const bh16* as = As[kc & 1];
#pragma unroll
    for (int ks = 0; ks < 4; ks++) {
      const bf16x8 bfr = *(const bf16x8*)(Wqk + (size_t)(w * 32 + l31) * CIN + kc * 64 + ks * 16 + hi * 8);
      const int kk = ks * 2 + hi;
#pragma unroll
      for (int nt = 0; nt < 2; nt++) {
        const int n = nt * 32 + l31;
        const bf16x8 a = *(const bf16x8*)&as[(size_t)(n * 8 + ((kk - n) & 7)) * 8];
        acc[nt] = __builtin_amdgcn_mfma_f32_32x32x16_bf16(a, bfr, acc[nt], 0, 0, 0);
      }
    }
    __syncthreads();
  }
#undef QK_STAGE
  const int o = w * 32 + l31;
  const float bo = bias128[o];
  if (w < 2) {
    // Q half: Qb[row][o], scaled by log2(e) so attn can use v_exp_f32 (2^x) directly
#pragma unroll
    for (int nt = 0; nt < 2; nt++)
#pragma unroll
      for (int r = 0; r < 16; r++) {
        const int nloc = nt * 32 + (r & 3) + 8 * (r >> 2) + 4 * hi;
        Qb[(size_t)(blk * 64 + nloc) * 64 + o] = (bh16)((acc[nt][r] + bo) * 1.44269504088896f);
      }
  } else {
    // K half: Kf[b][jtile][kg][j][8]
    const int b = blk >> 6, jtile = blk & 63;
    const int k = o - 64, kg = k >> 3, k7 = k & 7;
    bh16* kdst = Kf + (((size_t)(b * 64 + jtile) * 8 + kg) * 64) * 8 + k7;
#pragma unroll
    for (int nt = 0; nt < 2; nt++)
#pragma unroll
      for (int r = 0; r < 16; r++) {
        const int j = nt * 32 + (r & 3) + 8 * (r >> 2) + 4 * hi;
        kdst[(size_t)j * 8] = (bh16)(acc[nt][r] + bo);
      }
  }
}

// ---------- V projection via MFMA, output fragment-swizzled ----------
// Vf[b][ntile64][kgrp8][c512][8]  (kgrp = (n&63)>>3, elem = n&7)
__global__ __launch_bounds__(256) void v_proj_k(const bh16* __restrict__ xTb,
                                                const bh16* __restrict__ wvb,
                                                const float* __restrict__ bv,
                                                bh16* __restrict__ Vf) {
  const int nblk = blockIdx.x;  // 16
  const int cblk = blockIdx.y;  // 8
  const int b = blockIdx.z;
  const int t = threadIdx.x;
  const int w = t >> 6, l31 = t & 31, hi = (t & 63) >> 5;
  __shared__ __align__(16) bh16 Bs[2][256 * 64];  // [row n][slot*8] rotated
  f32x16 acc[2][2];
#pragma unroll
  for (int mt = 0; mt < 2; mt++)
#pragma unroll
    for (int nt = 0; nt < 2; nt++)
#pragma unroll
      for (int r = 0; r < 16; r++) acc[mt][nt][r] = 0.0f;

#define V_STAGE(kc, buf)                                                              \
  {                                                                                   \
    _Pragma("unroll") for (int i = 0; i < 8; i++) {                                   \
      const int s = i * 256 + t;                                                      \
      const int n = s >> 3, slot = s & 7;                                             \
      glds16(xTb + (size_t)(b * NPIX + nblk * 256 + n) * CIN + (kc) * 64 + (((slot + n) & 7) * 8), \
             &Bs[buf][(size_t)(i * 256 + w * 64) * 8]);                               \
    }                                                                                 \
  }

  V_STAGE(0, 0);
  __syncthreads();
  for (int kc = 0; kc < 8; kc++) {
    if (kc < 7) V_STAGE(kc + 1, (kc + 1) & 1);
    const bh16* bs = Bs[kc & 1];
#pragma unroll
    for (int ks = 0; ks < 4; ks++) {
      const int kk = ks * 2 + hi;
      bf16x8 a[2], bfr[2];
#pragma unroll
      for (int mt = 0; mt < 2; mt++)
        a[mt] = *(const bf16x8*)(wvb + (size_t)(cblk * 64 + mt * 32 + l31) * CIN + kc * 64 + ks * 16 + hi * 8);
#pragma unroll
      for (int nt = 0; nt < 2; nt++) {
        const int n = w * 64 + nt * 32 + l31;
        bfr[nt] = *(const bf16x8*)&bs[(size_t)(n * 8 + ((kk - n) & 7)) * 8];
      }
#pragma unroll
      for (int mt = 0; mt < 2; mt++)
#pragma unroll
        for (int nt = 0; nt < 2; nt++)
          acc[mt][nt] = __builtin_amdgcn_mfma_f32_32x32x16_bf16(a[mt], bfr[nt], acc[mt][nt], 0, 0, 0);
    }
    __syncthreads();
  }
#undef V_STAGE
  const int ntile0 = nblk * 4 + w;
#pragma unroll
  for (int mt = 0; mt < 2; mt++)
#pragma unroll
    for (int r = 0; r < 16; r++) {
      const int c = cblk * 64 + mt * 32 + (r & 3) + 8 * (r >> 2) + 4 * hi;
      const float bvc = bv[c];
#pragma unroll
      for (int nt = 0; nt < 2; nt++) {
        const int nl = nt * 32 + l31;  // n within the 64-tile
        Vf[(((size_t)(b * 64 + ntile0) * 8 + (nl >> 3)) * 512 + c) * 8 + (nl & 7)] =
            (bh16)(acc[mt][nt][r] + bvc);
      }
    }
}

// ---------- single-pass attention (no-max softmax) + residual -> pa [B][N][C] f16 ----------
// EXACT round-3 structure (97.1us, 112 VGPR, proven best) + T5 s_setprio around the
// MFMA+exp interleave (zero register cost, priority hint only).
// LEDGER of failed variants -- do not retry:
//  r1: #pragma unroll 2 -> live-range x2 -> 260MB scratch spill (2.2x slower)
//  r4: Ps b64-split layout -> 2x LDS instrs, +5us (its 2.1M conflicts were cheap)
//  r5: wave-split G2 (vf_use[4][4]) -> 192 nominal VGPR -> spill (+6.6MB writes, 1.5x)
// Rule: nominal register state must stay <= ~110 VGPR; reduce LDS *bytes* not at the
// cost of instruction count or registers.
__global__ __launch_bounds__(256, 2) void attn1p_k(const bh16* __restrict__ Qb,
                                                   const bh16* __restrict__ Kf,
                                                   const bh16* __restrict__ Vf,
                                                   const float* __restrict__ x,
                                                   fh16* __restrict__ pa,
                                                   float* __restrict__ psum,
                                                   float* __restrict__ pmax) {
  // XCD-aware remap: id%8 selects (b,cblk); id/8 selects mblk.
  const int id = blockIdx.x + 2 * (blockIdx.y + 64 * blockIdx.z);
  const int b = (id & 7) >> 1;
  const int cblk = id & 1;
  const int mblk = (id >> 3) * 64;
  const int t = threadIdx.x;
  const int w = t >> 6, l31 = t & 31, hi = (t >> 5) & 1;
  const int jhalf = w & 1, mhalf = w >> 1;
  __shared__ __align__(16) bh16 Ps[2][8 * 64 * 8];  // [buf][slot][m][8]  8KB each
  __shared__ float lred[4][32];
  __shared__ float linvL[64];

  // Q fragments (B-operand, col m = mhalf*32+l31), fixed for whole block
  bf16x8 qf[4];
  {
    const bh16* qrow = Qb + (size_t)(b * NPIX + mblk + mhalf * 32 + l31) * 64;
#pragma unroll
    for (int ks = 0; ks < 4; ks++) qf[ks] = *(const bf16x8*)(qrow + ks * 16 + hi * 8);
  }
  const bh16* kfb = Kf + (size_t)b * (64 * 8 * 64 * 8);
  const bh16* vfb = Vf + (size_t)b * (64 * 8 * 512 * 8);
  const int cbase = cblk * 256 + w * 64;

#define KADDR(tile, ks) (kfb + (((size_t)(tile) * 8 + (ks) * 2 + hi) * 64 + jhalf * 32 + l31) * 8)
#define VADDR(tile, ks, ct) (vfb + (((size_t)(tile) * 8 + (ks) * 2 + hi) * 512 + cbase + (ct) * 32 + l31) * 8)

  f32x16 acc[2][2];
#pragma unroll
  for (int mt = 0; mt < 2; mt++)
#pragma unroll
    for (int ct = 0; ct < 2; ct++)
#pragma unroll
      for (int r = 0; r < 16; r++) acc[mt][ct][r] = 0.0f;
  float4 lsacc;
  lsacc.x = 0.0f; lsacc.y = 0.0f; lsacc.z = 0.0f; lsacc.w = 0.0f;

  // pipeline registers (single-buffered, reload-after-last-use)
  bf16x8 kf_nxt[4];       // K(it+1) at top of iter it
  bf16x8 vf_use[4][2];    // V(it-1) at top of iter it
  f32x16 s1;              // raw S(it)
  {
    bf16x8 k0[4];
#pragma unroll
    for (int ks = 0; ks < 4; ks++) {
      k0[ks] = *(const bf16x8*)KADDR(0, ks);
#pragma unroll
      for (int ct = 0; ct < 2; ct++) vf_use[ks][ct] = *(const bf16x8*)VADDR(0, ks, ct);
    }
#pragma unroll
    for (int ks = 0; ks < 4; ks++) kf_nxt[ks] = *(const bf16x8*)KADDR(1, ks);
#pragma unroll
    for (int r = 0; r < 16; r++) s1[r] = 0.0f;
#pragma unroll
    for (int ks = 0; ks < 4; ks++)
      s1 = __builtin_amdgcn_mfma_f32_32x32x16_bf16(k0[ks], qf[ks], s1, 0, 0, 0);
  }

  for (int it = 0; it < 64; it++) {
    __builtin_amdgcn_s_setprio(1);
    // G1 for it+1 (result for next iteration; garbage at it=63, unused)
    f32x16 s1n;
#pragma unroll
    for (int r = 0; r < 16; r++) s1n[r] = 0.0f;
#pragma unroll
    for (int ks = 0; ks < 4; ks++)
      s1n = __builtin_amdgcn_mfma_f32_32x32x16_bf16(kf_nxt[ks], qf[ks], s1n, 0, 0, 0);
    // kf_nxt dead now -> reload K(it+2) immediately (cover = rest of body + barrier)
    {
      const int kt = (it + 2 < 64) ? it + 2 : 63;
#pragma unroll
      for (int ks = 0; ks < 4; ks++) kf_nxt[ks] = *(const bf16x8*)KADDR(kt, ks);
    }

    const bh16* ps = Ps[(it + 1) & 1];  // == (it-1)&1
    bh16* psw = Ps[it & 1];
    if (it) {
      // G2(it-1) [MFMA] interleaved with exp/pack(it) [VALU] -- independent
#pragma unroll
      for (int ks = 0; ks < 4; ks++) {
        bf16x8 pf0 = *(const bf16x8*)&ps[(size_t)((ks * 2 + hi) * 64 + l31) * 8];
        bf16x8 pf1 = *(const bf16x8*)&ps[(size_t)((ks * 2 + hi) * 64 + 32 + l31) * 8];
        acc[0][0] = __builtin_amdgcn_mfma_f32_32x32x16_bf16(pf0, vf_use[ks][0], acc[0][0], 0, 0, 0);
        acc[0][1] = __builtin_amdgcn_mfma_f32_32x32x16_bf16(pf0, vf_use[ks][1], acc[0][1], 0, 0, 0);
        // one exp/pack group between MFMA clusters
        {
          union { bh16 h[4]; uint2 u2; } pk;
#pragma unroll
          for (int q = 0; q < 4; q++) {
            const float p = fexp2(s1[ks * 4 + q]);
            lsacc[q] += p;
            pk.h[q] = (bh16)p;
          }
          *(uint2*)(void*)&psw[(size_t)((jhalf * 4 + ks) * 64 + mhalf * 32 + l31) * 8 + hi * 4] = pk.u2;
        }
        acc[1][0] = __builtin_amdgcn_mfma_f32_32x32x16_bf16(pf1, vf_use[ks][0], acc[1][0], 0, 0, 0);
        acc[1][1] = __builtin_amdgcn_mfma_f32_32x32x16_bf16(pf1, vf_use[ks][1], acc[1][1], 0, 0, 0);
        // vf_use[ks] dead now -> reload V(it) for next iteration's G2 (~1-iter cover)
        vf_use[ks][0] = *(const bf16x8*)VADDR(it, ks, 0);
        vf_use[ks][1] = *(const bf16x8*)VADDR(it, ks, 1);
      }
    } else {
#pragma unroll
      for (int g = 0; g < 4; g++) {
        union { bh16 h[4]; uint2 u2; } pk;
#pragma unroll
        for (int q = 0; q < 4; q++) {
          const float p = fexp2(s1[g * 4 + q]);
          lsacc[q] += p;
          pk.h[q] = (bh16)p;
        }
        *(uint2*)(void*)&psw[(size_t)((jhalf * 4 + g) * 64 + mhalf * 32 + l31) * 8 + hi * 4] = pk.u2;
      }
      // vf_use keeps prologue-loaded V(0) for iter 1's G2
    }
    __builtin_amdgcn_s_setprio(0);
    __syncthreads();  // P(it) visible; loads below get a full iteration of cover
    s1 = s1n;
  }
  // final G2: P(63) x V(63)
  {
    const bh16* ps = Ps[1];
#pragma unroll
    for (int ks = 0; ks < 4; ks++) {
      bf16x8 pf0 = *(const bf16x8*)&ps[(size_t)((ks * 2 + hi) * 64 + l31) * 8];
      bf16x8 pf1 = *(const bf16x8*)&ps[(size_t)((ks * 2 + hi) * 64 + 32 + l31) * 8];
      acc[0][0] = __builtin_amdgcn_mfma_f32_32x32x16_bf16(pf0, vf_use[ks][0], acc[0][0], 0, 0, 0);
      acc[0][1] = __builtin_amdgcn_mfma_f32_32x32x16_bf16(pf0, vf_use[ks][1], acc[0][1], 0, 0, 0);
      acc[1][0] = __builtin_amdgcn_mfma_f32_32x32x16_bf16(pf1, vf_use[ks][0], acc[1][0], 0, 0, 0);
      acc[1][1] = __builtin_amdgcn_mfma_f32_32x32x16_bf16(pf1, vf_use[ks][1], acc[1][1], 0, 0, 0);
    }
  }
#undef KADDR
#undef VADDR

  // reduce row-sums: lanes (hi) within wave, then across jhalf wave pairs
  float lsum = (lsacc.x + lsacc.y) + (lsacc.z + lsacc.w);
  lsum += __shfl_xor(lsum, 32);
  if (hi == 0) lred[w][l31] = lsum;
  __syncthreads();
  if (t < 64) linvL[t] = 1.0f / (lred[(t >> 5) * 2][t & 31] + lred[(t >> 5) * 2 + 1][t & 31]);
  __syncthreads();

  // epilogue: normalize + residual, write pa[B][N][C] f16 + pooling partials
  float csum[2] = {0.0f, 0.0f};
  float cmax[2] = {-1e30f, -1e30f};
#pragma unroll
  for (int mt = 0; mt < 2; mt++) {
#pragma unroll
    for (int g = 0; g < 4; g++) {
      const int mloc = mt * 32 + g * 8 + hi * 4;
      const float4 lv = *(const float4*)&linvL[mloc];
#pragma unroll
      for (int ct = 0; ct < 2; ct++) {
        const int c = cbase + ct * 32 + l31;
        const float4 xv = *(const float4*)&x[(size_t)(b * CIN + c) * NPIX + mblk + mloc];
        float r0 = acc[mt][ct][g * 4 + 0] * lv.x + xv.x;
        float r1 = acc[mt][ct][g * 4 + 1] * lv.y + xv.y;
        float r2 = acc[mt][ct][g * 4 + 2] * lv.z + xv.z;
        float r3 = acc[mt][ct][g * 4 + 3] * lv.w + xv.w;
        csum[ct] += (r0 + r1) + (r2 + r3);
        cmax[ct] = fmaxf(cmax[ct], fmaxf(fmaxf(r0, r1), fmaxf(r2, r3)));
        fh16* pd = pa + ((size_t)(b * NPIX) + mblk + mloc) * CIN + c;
        pd[0 * CIN] = (fh16)r0;
        pd[1 * CIN] = (fh16)r1;
        pd[2 * CIN] = (fh16)r2;
        pd[3 * CIN] = (fh16)r3;
      }
    }
  }
  // combine hi halves (each holds 32 of the 64 pixels for the same c)
#pragma unroll
  for (int ct = 0; ct < 2; ct++) {
    csum[ct] += __shfl_xor(csum[ct], 32);
    cmax[ct] = fmaxf(cmax[ct], __shfl_xor(cmax[ct], 32));
  }
  if (hi == 0) {
    const int mb = mblk >> 6;
#pragma unroll
    for (int ct = 0; ct < 2; ct++) {
      const int c = cbase + ct * 32 + l31;
      psum[((size_t)b * 64 + mb) * CIN + c] = csum[ct];
      pmax[((size_t)b * 64 + mb) * CIN + c] = cmax[ct];
    }
  }
}

// ---------- channel-attention MLP (with fused partial-pool reduce) -> sigmoid scale ----------
__global__ __launch_bounds__(256) void mlp2_k(const float* __restrict__ psum,
                                              const float* __restrict__ pmax,
                                              const float* __restrict__ w1,
                                              const float* __restrict__ w2,
                                              float* __restrict__ scale) {
  const int b = blockIdx.x;
  const int t = threadIdx.x;
  __shared__ float avg_l[CIN], max_l[CIN], hbuf[128];
#pragma unroll
  for (int h = 0; h < 2; h++) {
    const int c = t + h * 256;
    float s = 0.0f, m = -1e30f;
#pragma unroll
    for (int k = 0; k < 64; k++) {
      s += psum[((size_t)b * 64 + k) * CIN + c];
      m = fmaxf(m, pmax[((size_t)b * 64 + k) * CIN + c]);
    }
    avg_l[c] = s * (1.0f / 4096.0f);
    max_l[c] = m;
  }
  __syncthreads();
  if (t < 128) {
    const float* src = (t < 64) ? avg_l : max_l;
    const int o = t & 63;
    float sacc = 0.0f;
    for (int c = 0; c < CIN; c += 4) {
      const float4 wv = *(const float4*)&w1[o * CIN + c];
      sacc += wv.x * src[c] + wv.y * src[c + 1] + wv.z * src[c + 2] + wv.w * src[c + 3];
    }
    hbuf[t] = fmaxf(sacc, 0.0f);
  }
  __syncthreads();
#pragma unroll
  for (int h = 0; h < 2; h++) {
    const int c = t + h * 256;
    float sacc = 0.0f;
#pragma unroll
    for (int k = 0; k < 64; k += 4) {
      const float4 wv = *(const float4*)&w2[c * 64 + k];
      sacc += wv.x * (hbuf[k] + hbuf[64 + k]) + wv.y * (hbuf[k + 1] + hbuf[64 + k + 1]) +
              wv.z * (hbuf[k + 2] + hbuf[64 + k + 2]) + wv.w * (hbuf[k + 3] + hbuf[64 + k + 3]);
    }
    scale[b * CIN + c] = 1.0f / (1.0f + __expf(-sacc));
  }
}

// ---------- pack pa[B][N][C] f16 * scale -> f16 padded pixel-major [B][66*66][512] ----------
// Same inner (channel) layout on both sides: pure coalesced row copy with per-ch scale.
__global__ __launch_bounds__(256) void pack_k(const fh16* __restrict__ pa,
                                              const float* __restrict__ scl,
                                              fh16* __restrict__ pab) {
  const int b = blockIdx.y;
  const int n0 = blockIdx.x * 8;
  const int t = threadIdx.x;
  __shared__ float sc[CIN];
#pragma unroll
  for (int h = 0; h < 2; h++) sc[t + h * 256] = scl[b * CIN + t + h * 256];
  __syncthreads();
  const int c2 = t * 2;
  const float s0 = sc[c2], s1 = sc[c2 + 1];
#pragma unroll
  for (int j = 0; j < 8; j++) {
    const int n = n0 + j;
    const int pp = ((n >> 6) + 1) * 66 + (n & 63) + 1;
    union { fh16 h[2]; unsigned int u; } v, o;
    v.u = *(const unsigned int*)(pa + ((size_t)b * NPIX + n) * CIN + c2);
    o.h[0] = (fh16)((float)v.h[0] * s0);
    o.h[1] = (fh16)((float)v.h[1] * s1);
    *(unsigned int*)(void*)(pab + ((size_t)b * PPIX + pp) * CIN + c2) = o.u;
  }
}

// ---------- zero the SAME-padding borders of pab (interior written by pack_k) ----------
// 260 border pixels per image: row0 (66), row65 (66), col0 rows1-64 (64), col65 rows1-64 (64)
__global__ __launch_bounds__(256) void bzero_k(fh16* __restrict__ pab) {
  const int t = threadIdx.x;
  const int p = blockIdx.x * 4 + (t >> 6);  // 0..259
  const int b = blockIdx.y;
  int pp;
  if (p < 66) pp = p;
  else if (p < 132) pp = 65 * 66 + (p - 66);
  else if (p < 196) pp = (p - 131) * 66;
  else pp = (p - 195) * 66 + 65;
  uint4 z = {0u, 0u, 0u, 0u};
  *(uint4*)(void*)(pab + ((size_t)b * PPIX + pp) * CIN + (t & 63) * 8) = z;
}

// ---------- repack conv weights -> f16 [oblk4][chunk32][tap9][chalf2][o64][8] ----------
// chalf-major over o gives the conv kernel 16B-lane-stride LDS reads (no 2x bank waste)
__global__ __launch_bounds__(256) void wpack_k(const float* __restrict__ cw,
                                               fh16* __restrict__ wp) {
  const int slot = blockIdx.x * 256 + threadIdx.x;  // one 8-f16 group
  const int oblk = slot / 36864;
  const int r1 = slot - oblk * 36864;
  const int chunk = r1 / 1152;
  const int r2 = r1 - chunk * 1152;
  const int tap = r2 >> 7;
  const int r3 = r2 & 127;
  const int h = r3 >> 6;
  const int o = r3 & 63;
  const size_t sbase = (size_t)(oblk * 64 + o) * 4608 + (size_t)(chunk * 16 + h * 8) * 9 + tap;
  union { fh16 h8[8]; uint4 u4; } pk;
#pragma unroll
  for (int i = 0; i < 8; i++) pk.h8[i] = (fh16)cw[sbase + (size_t)i * 9];
  *(uint4*)(void*)(wp + (size_t)slot * 8) = pk.u4;
}

// ---------- implicit-GEMM 3x3 conv via f16 MFMA + BN + ReLU ----------
// Xs layout [batch13][chalf2][row32][8], Ws layout [tap9][chalf2][o64][8]:
// all ds_read_b128 at 16B lane stride (full 32-bank sweep) instead of 32B (half banks).
__global__ __launch_bounds__(256) void conv_mfma_k(const fh16* __restrict__ pab,
                                                   const fh16* __restrict__ wp,
                                                   const float* __restrict__ gamma,
                                                   const float* __restrict__ beta,
                                                   const float* __restrict__ mean,
                                                   const float* __restrict__ var,
                                                   float* __restrict__ out) {
  const int y0 = blockIdx.x * 4;
  const int oblk = blockIdx.y;
  const int b = blockIdx.z;
  const int t = threadIdx.x;
  const int w = t >> 6, lane = t & 63, l31 = lane & 31, hi = lane >> 5;
  __shared__ __align__(16) fh16 Xs[2][416 * 16];
  __shared__ __align__(16) fh16 Ws[2][9 * 64 * 16];
  __shared__ float sb[64], bb[64];
  if (t < 64) {
    const int o = oblk * 64 + t;
    const float inv = rsqrtf(var[o] + 1e-5f);
    const float sc = inv * gamma[o];
    sb[t] = sc;
    bb[t] = beta[o] - mean[o] * sc;
  }
  f32x16 o00, o01, o10, o11;
#pragma unroll
  for (int r = 0; r < 16; r++) { o00[r] = 0.0f; o01[r] = 0.0f; o10[r] = 0.0f; o11[r] = 0.0f; }

  // lane -> (row-in-batch = lane&31, chalf = lane>>5): LDS dest is linear, so the
  // [batch][chalf][row][8] layout is created purely by the per-lane GLOBAL address.
  const fh16* xbase = pab + ((size_t)b * PPIX + y0 * 66) * CIN + (size_t)(lane & 31) * CIN + (lane >> 5) * 8;
  const fh16* wbase = wp + (size_t)oblk * 32 * 9216 + lane * 8;

#define STAGE(chunk, buf)                                                        \
  {                                                                              \
    const fh16* xs = xbase + (chunk) * 16;                                       \
    for (int i = w; i < 13; i += 4)                                              \
      glds16(xs + (size_t)i * 32 * CIN, &Xs[buf][i * 512]);                      \
    const fh16* wsrc = wbase + (size_t)(chunk) * 9216;                           \
    for (int i = w; i < 18; i += 4)                                              \
      glds16(wsrc + (size_t)i * 512, &Ws[buf][i * 512]);                         \
  }

  STAGE(0, 0);
  __syncthreads();
  for (int chunk = 0; chunk < 32; chunk++) {
    if (chunk < 31) STAGE(chunk + 1, (chunk + 1) & 1);
    const fh16* xs = Xs[chunk & 1];
    const fh16* ws = Ws[chunk & 1];
#pragma unroll
    for (int tap = 0; tap < 9; tap++) {
      const int ky = tap / 3, kx = tap - ky * 3;
      const f16x8 a0 = *(const f16x8*)&ws[tap * 1024 + hi * 512 + l31 * 8];
      const f16x8 a1 = *(const f16x8*)&ws[tap * 1024 + hi * 512 + (32 + l31) * 8];
      const int row0 = (w + ky) * 66 + l31 + kx;
      const int row1 = row0 + 32;
      const f16x8 b0 = *(const f16x8*)&xs[(row0 >> 5) * 512 + hi * 256 + (row0 & 31) * 8];
      const f16x8 b1 = *(const f16x8*)&xs[(row1 >> 5) * 512 + hi * 256 + (row1 & 31) * 8];
      o00 = __builtin_amdgcn_mfma_f32_32x32x16_f16(a0, b0, o00, 0, 0, 0);
      o01 = __builtin_amdgcn_mfma_f32_32x32x16_f16(a0, b1, o01, 0, 0, 0);
      o10 = __builtin_amdgcn_mfma_f32_32x32x16_f16(a1, b0, o10, 0, 0, 0);
      o11 = __builtin_amdgcn_mfma_f32_32x32x16_f16(a1, b1, o11, 0, 0, 0);
    }
    __syncthreads();
  }
#undef STAGE

  const f32x16* accs[2][2] = {{&o00, &o01}, {&o10, &o11}};
#pragma unroll
  for (int mt = 0; mt < 2; mt++) {
#pragma unroll
    for (int nt = 0; nt < 2; nt++) {
      const f32x16& A = *accs[mt][nt];
#pragma unroll
      for (int r = 0; r < 16; r++) {
        const int cl = mt * 32 + (r & 3) + 8 * (r >> 2) + 4 * hi;
        const int pix = nt * 32 + l31;
        const float y = A[r] * sb[cl] + bb[cl];
        out[((size_t)(b * COUT + oblk * 64 + cl)) * NPIX + (y0 + w) * 64 + pix] = fmaxf(y, 0.0f);
      }
    }
  }
}

extern "C" void kernel_launch(void* const* d_in, const int* in_sizes, int n_in,
                              void* d_out, int out_size, void* d_ws, size_t ws_size,
                              hipStream_t stream) {
  (void)in_sizes; (void)n_in; (void)out_size; (void)ws_size;
  const float* x        = (const float*)d_in[0];
  const float* wq       = (const float*)d_in[1];
  const float* bq       = (const float*)d_in[2];
  const float* wk       = (const float*)d_in[3];
  const float* bk       = (const float*)d_in[4];
  const float* wv       = (const float*)d_in[5];
  const float* bv       = (const float*)d_in[6];
  const float* ca_w1    = (const float*)d_in[7];
  const float* ca_w2    = (const float*)d_in[8];
  const float* conv_w   = (const float*)d_in[9];
  const float* bn_gamma = (const float*)d_in[10];
  const float* bn_beta  = (const float*)d_in[11];
  const float* bn_mean  = (const float*)d_in[12];
  const float* bn_var   = (const float*)d_in[13];
  float* out = (float*)d_out;

  float* ws = (float*)d_ws;
  fh16*  pa      = (fh16*)ws;                   // [B][N][C] f16 (16.8 MB)
  float* psum    = ws + 4194304;                // [B][64][C] fp32 partial sums (512 KB)
  float* pmax    = ws + 4325376;                // [B][64][C] fp32 partial maxes (512 KB)
  bh16*  Vf      = (bh16*)(ws + 8388608);       // [B][64][8][512][8] bf16 (aliased by wpck later)
  fh16*  wpck    = (fh16*)(ws + 8388608);       // conv weights f16 (after attn)
  bh16*  Qb      = (bh16*)(ws + 12582912);      // [B*N][64] bf16
  bh16*  Kf      = (bh16*)(ws + 13107200);      // [B][64][8][64][8] bf16
  bh16*  xTb     = (bh16*)(ws + 13631488);      // [B][N][C] bf16 (aliased by pab later)
  fh16*  pab     = (fh16*)(ws + 13631488);      // [B][4356][512] f16 + pad
  bh16*  Wqk     = (bh16*)(ws + 17825792);      // [128][512] bf16
  bh16*  wvb     = (bh16*)(ws + 17858560);      // [512][512] bf16
  float* bias128 = ws + 17989632;
  float* scl     = ws + 18104320;

  wcast_k<<<dim3(1280, 1, 1), 256, 0, stream>>>(wq, wk, wv, bq, bk, Wqk, wvb, bias128);
  transpose_bf_k<<<dim3(NPIX / 64, CIN / 64, NB), 256, 0, stream>>>(x, xTb);
  qk_proj_k<<<dim3(256, 1, 1), 256, 0, stream>>>(xTb, Wqk, bias128, Qb, Kf);
  v_proj_k<<<dim3(16, 8, NB), 256, 0, stream>>>(xTb, wvb, bv, Vf);
  attn1p_k<<<dim3(2, 64, NB), 256, 0, stream>>>(Qb, Kf, Vf, x, pa, psum, pmax);
  // xTb dead now: zero only the conv SAME-padding borders (pack_k writes all interior;
  // staging over-reads past pab land in allocated pad and are never consumed)
  bzero_k<<<dim3(65, NB, 1), 256, 0, stream>>>(pab);
  mlp2_k<<<dim3(NB, 1, 1), 256, 0, stream>>>(psum, pmax, ca_w1, ca_w2, scl);
  pack_k<<<dim3(NPIX / 8, NB, 1), 256, 0, stream>>>(pa, scl, pab);
  wpack_k<<<dim3(576, 1, 1), 256, 0, stream>>>(conv_w, wpck);  // Vf dead now
  conv_mfma_k<<<dim3(16, 4, NB), 256, 0, stream>>>(pab, wpck, bn_gamma, bn_beta,
                                                   bn_mean, bn_var, out);
}

// Round 7
// 318.374 us; speedup vs baseline: 1.1192x; 1.0324x over previous
//
#include <hip/hip_runtime.h>

#define NB 4
#define CIN 512
#define NPIX 4096
#define CQK 64
#define COUT 256
#define PPIX 4356   // 66*66 padded pixels

typedef __bf16 bh16;
typedef _Float16 fh16;
typedef __attribute__((ext_vector_type(8))) __bf16 bf16x8;
typedef __attribute__((ext_vector_type(8))) _Float16 f16x8;
typedef __attribute__((ext_vector_type(16))) float f32x16;

#define AS1 __attribute__((address_space(1)))
#define AS3 __attribute__((address_space(3)))

__device__ __forceinline__ void glds16(const void* g, void* l) {
  __builtin_amdgcn_global_load_lds((const AS1 unsigned int*)g, (AS3 unsigned int*)l, 16, 0, 0);
}

// LDS-only barrier: orders ds_write/ds_read across waves WITHOUT draining vmcnt,
// so plain global loads (K/V prefetches into VGPRs) stay in flight across it.
__device__ __forceinline__ void lbar() {
  asm volatile("s_waitcnt lgkmcnt(0)\n\ts_barrier" ::: "memory");
}

// 2^x (Q is pre-scaled by log2e so attention needs exp2, not exp)
__device__ __forceinline__ float fexp2(float x) {
#if __has_builtin(__builtin_amdgcn_exp2f)
  return __builtin_amdgcn_exp2f(x);
#else
  return __expf(x * 0.6931471805599453f);
#endif
}

// ---------- transpose x [B][C][N] -> xTb [B][N][C] bf16 ----------
// 64x64 tile: float4 coalesced reads (256B/16-lane group), ushort4 writes (128B).
__global__ __launch_bounds__(256) void transpose_bf_k(const float* __restrict__ src,
                                                      bh16* __restrict__ dst) {
  __shared__ float tile[64][65];
  const int b = blockIdx.z;
  const int n0 = blockIdx.x * 64;   // N tile
  const int c0 = blockIdx.y * 64;   // C tile
  const float* s = src + (size_t)b * CIN * NPIX;
  bh16* d = dst + (size_t)b * CIN * NPIX;
  const int t = threadIdx.x;
  const int q4 = (t & 15) * 4;
  const int rr = t >> 4;
#pragma unroll
  for (int i = 0; i < 4; i++) {
    const int c = rr + i * 16;
    const float4 v = *(const float4*)&s[(size_t)(c0 + c) * NPIX + n0 + q4];
    tile[q4 + 0][c] = v.x;
    tile[q4 + 1][c] = v.y;
    tile[q4 + 2][c] = v.z;
    tile[q4 + 3][c] = v.w;
  }
  __syncthreads();
#pragma unroll
  for (int i = 0; i < 4; i++) {
    const int n = rr + i * 16;
    union { bh16 h[4]; ushort4 u; } pk;
    pk.h[0] = (bh16)tile[n][q4 + 0];
    pk.h[1] = (bh16)tile[n][q4 + 1];
    pk.h[2] = (bh16)tile[n][q4 + 2];
    pk.h[3] = (bh16)tile[n][q4 + 3];
    *(ushort4*)(void*)&d[(size_t)(n0 + n) * CIN + c0 + q4] = pk.u;
  }
}

// ---------- cast weights to bf16: Wqk[128][512] = [wq;wk], wvb[512][512], bias128 ----------
__global__ __launch_bounds__(256) void wcast_k(const float* __restrict__ wq,
                                               const float* __restrict__ wk,
                                               const float* __restrict__ wv,
                                               const float* __restrict__ bq,
                                               const float* __restrict__ bk,
                                               bh16* __restrict__ Wqk,
                                               bh16* __restrict__ wvb,
                                               float* __restrict__ bias128) {
  const int idx = blockIdx.x * 256 + threadIdx.x;
  if (idx < 65536) {
    Wqk[idx] = (bh16)(idx < 32768 ? wq[idx] : wk[idx - 32768]);
  } else {
    const int j = idx - 65536;
    wvb[j] = (bh16)wv[j];
  }
  if (idx < 128) bias128[idx] = idx < 64 ? bq[idx] : bk[idx - 64];
}

// ---------- Q|K projection via MFMA ----------
// Q half -> Qb [B*N][64] row-major, PRE-SCALED by log2(e); K half -> Kf fragment-swizzled:
// Kf[b][jtile64][kgrp8][j64][8]  (kgrp = k>>3, elem = k&7)
__global__ __launch_bounds__(256) void qk_proj_k(const bh16* __restrict__ xTb,
                                                 const bh16* __restrict__ Wqk,
                                                 const float* __restrict__ bias128,
                                                 bh16* __restrict__ Qb,
                                                 bh16* __restrict__ Kf) {
  const int blk = blockIdx.x;  // 256 blocks of 64 rows
  const int t = threadIdx.x;
  const int w = t >> 6, l31 = t & 31, hi = (t & 63) >> 5;
  __shared__ __align__(16) bh16 As[2][64 * 64];  // [row][slot*8] rotated
  f32x16 acc[2];
#pragma unroll
  for (int nt = 0; nt < 2; nt++)
#pragma unroll
    for (int r = 0; r < 16; r++) acc[nt][r] = 0.0f;

#define QK_STAGE(kc, buf)                                                           \
  {                                                                                 \
    _Pragma("unroll") for (int i = 0; i < 2; i++) {                                 \
      const int s = i * 256 + t;                                                    \
      const int n = s >> 3, slot = s & 7;                                           \
      glds16(xTb + (size_t)(blk * 64 + n) * CIN + (kc) * 64 + (((slot + n) & 7) * 8), \
             &As[buf][(size_t)(i * 256 + w * 64) * 8]);                             \
    }                                                                               \
  }

  QK_STAGE(0, 0);
  __syncthreads();
  for (int kc = 0; kc < 8; kc++) {
    if (kc < 7) QK_STAGE(kc + 1, (kc + 1) & 1);
    const bh16* as = As[kc & 1];
#pragma unroll
    for (int ks = 0; ks < 4; ks++) {
      const bf16x8 bfr = *(const bf16x8*)(Wqk + (size_t)(w * 32 + l31) * CIN + kc * 64 + ks * 16 + hi * 8);
      const int kk = ks * 2 + hi;
#pragma unroll
      for (int nt = 0; nt < 2; nt++) {
        const int n = nt * 32 + l31;
        const bf16x8 a = *(const bf16x8*)&as[(size_t)(n * 8 + ((kk - n) & 7)) * 8];
        acc[nt] = __builtin_amdgcn_mfma_f32_32x32x16_bf16(a, bfr, acc[nt], 0, 0, 0);
      }
    }
    __syncthreads();
  }
#undef QK_STAGE
  const int o = w * 32 + l31;
  const float bo = bias128[o];
  if (w < 2) {
    // Q half: Qb[row][o], scaled by log2(e) so attn can use v_exp_f32 (2^x) directly
#pragma unroll
    for (int nt = 0; nt < 2; nt++)
#pragma unroll
      for (int r = 0; r < 16; r++) {
        const int nloc = nt * 32 + (r & 3) + 8 * (r >> 2) + 4 * hi;
        Qb[(size_t)(blk * 64 + nloc) * 64 + o] = (bh16)((acc[nt][r] + bo) * 1.44269504088896f);
      }
  } else {
    // K half: Kf[b][jtile][kg][j][8]
    const int b = blk >> 6, jtile = blk & 63;
    const int k = o - 64, kg = k >> 3, k7 = k & 7;
    bh16* kdst = Kf + (((size_t)(b * 64 + jtile) * 8 + kg) * 64) * 8 + k7;
#pragma unroll
    for (int nt = 0; nt < 2; nt++)
#pragma unroll
      for (int r = 0; r < 16; r++) {
        const int j = nt * 32 + (r & 3) + 8 * (r >> 2) + 4 * hi;
        kdst[(size_t)j * 8] = (bh16)(acc[nt][r] + bo);
      }
  }
}

// ---------- V projection via MFMA, output fragment-swizzled ----------
// Vf[b][ntile64][kgrp8][c512][8]  (kgrp = (n&63)>>3, elem = n&7)
__global__ __launch_bounds__(256) void v_proj_k(const bh16* __restrict__ xTb,
                                                const bh16* __restrict__ wvb,
                                                const float* __restrict__ bv,
                                                bh16* __restrict__ Vf) {
  const int nblk = blockIdx.x;  // 16
  const int cblk = blockIdx.y;  // 8
  const int b = blockIdx.z;
  const int t = threadIdx.x;
  const int w = t >> 6, l31 = t & 31, hi = (t & 63) >> 5;
  __shared__ __align__(16) bh16 Bs[2][256 * 64];  // [row n][slot*8] rotated
  f32x16 acc[2][2];
#pragma unroll
  for (int mt = 0; mt < 2; mt++)
#pragma unroll
    for (int nt = 0; nt < 2; nt++)
#pragma unroll
      for (int r = 0; r < 16; r++) acc[mt][nt][r] = 0.0f;

#define V_STAGE(kc, buf)                                                              \
  {                                                                                   \
    _Pragma("unroll") for (int i = 0; i < 8; i++) {                                   \
      const int s = i * 256 + t;                                                      \
      const int n = s >> 3, slot = s & 7;                                             \
      glds16(xTb + (size_t)(b * NPIX + nblk * 256 + n) * CIN + (kc) * 64 + (((slot + n) & 7) * 8), \
             &Bs[buf][(size_t)(i * 256 + w * 64) * 8]);                               \
    }                                                                                 \
  }

  V_STAGE(0, 0);
  __syncthreads();
  for (int kc = 0; kc < 8; kc++) {
    if (kc < 7) V_STAGE(kc + 1, (kc + 1) & 1);
    const bh16* bs = Bs[kc & 1];
#pragma unroll
    for (int ks = 0; ks < 4; ks++) {
      const int kk = ks * 2 + hi;
      bf16x8 a[2], bfr[2];
#pragma unroll
      for (int mt = 0; mt < 2; mt++)
        a[mt] = *(const bf16x8*)(wvb + (size_t)(cblk * 64 + mt * 32 + l31) * CIN + kc * 64 + ks * 16 + hi * 8);
#pragma unroll
      for (int nt = 0; nt < 2; nt++) {
        const int n = w * 64 + nt * 32 + l31;
        bfr[nt] = *(const bf16x8*)&bs[(size_t)(n * 8 + ((kk - n) & 7)) * 8];
      }
#pragma unroll
      for (int mt = 0; mt < 2; mt++)
#pragma unroll
        for (int nt = 0; nt < 2; nt++)
          acc[mt][nt] = __builtin_amdgcn_mfma_f32_32x32x16_bf16(a[mt], bfr[nt], acc[mt][nt], 0, 0, 0);
    }
    __syncthreads();
  }
#undef V_STAGE
  const int ntile0 = nblk * 4 + w;
#pragma unroll
  for (int mt = 0; mt < 2; mt++)
#pragma unroll
    for (int r = 0; r < 16; r++) {
      const int c = cblk * 64 + mt * 32 + (r & 3) + 8 * (r >> 2) + 4 * hi;
      const float bvc = bv[c];
#pragma unroll
      for (int nt = 0; nt < 2; nt++) {
        const int nl = nt * 32 + l31;  // n within the 64-tile
        Vf[(((size_t)(b * 64 + ntile0) * 8 + (nl >> 3)) * 512 + c) * 8 + (nl & 7)] =
            (bh16)(acc[mt][nt][r] + bvc);
      }
    }
}

// ---------- single-pass attention (no-max softmax) + residual -> pa [B][N][C] f16 ----------
// Round-3 structure (97.1us, proven best) with two zero-register deltas:
//  (a) lbar() instead of __syncthreads in the main loop: the 12 K/V VGPR loads per
//      iteration stay in flight across the barrier (no vmcnt(0) drain).
//  (b) kt unclamped (it+2): reads <=16KB past Kf land in allocated xTb; garbage only
//      reaches the discarded it=63 s1n. Enables strength-reduced addressing.
// LEDGER of failed variants -- do not retry:
//  r1: #pragma unroll 2 -> live-range x2 -> 260MB scratch spill (2.2x slower)
//  r4: Ps b64-split layout -> 2x LDS instrs, +5us (its 2.1M conflicts are cheap)
//  r5: wave-split G2 (vf_use[4][4]) -> 192 nominal VGPR -> spill (1.5x slower)
//  r6: s_setprio(1) -> neutral (+1us; waves are barrier-locked, nothing to arbitrate)
// Rule: nominal register state must stay <= ~110 VGPR.
__global__ __launch_bounds__(256, 2) void attn1p_k(const bh16* __restrict__ Qb,
                                                   const bh16* __restrict__ Kf,
                                                   const bh16* __restrict__ Vf,
                                                   const float* __restrict__ x,
                                                   fh16* __restrict__ pa,
                                                   float* __restrict__ psum,
                                                   float* __restrict__ pmax) {
  // XCD-aware remap: id%8 selects (b,cblk); id/8 selects mblk.
  const int id = blockIdx.x + 2 * (blockIdx.y + 64 * blockIdx.z);
  const int b = (id & 7) >> 1;
  const int cblk = id & 1;
  const int mblk = (id >> 3) * 64;
  const int t = threadIdx.x;
  const int w = t >> 6, l31 = t & 31, hi = (t >> 5) & 1;
  const int jhalf = w & 1, mhalf = w >> 1;
  __shared__ __align__(16) bh16 Ps[2][8 * 64 * 8];  // [buf][slot][m][8]  8KB each
  __shared__ float lred[4][32];
  __shared__ float linvL[64];

  // Q fragments (B-operand, col m = mhalf*32+l31), fixed for whole block
  bf16x8 qf[4];
  {
    const bh16* qrow = Qb + (size_t)(b * NPIX + mblk + mhalf * 32 + l31) * 64;
#pragma unroll
    for (int ks = 0; ks < 4; ks++) qf[ks] = *(const bf16x8*)(qrow + ks * 16 + hi * 8);
  }
  const bh16* kfb = Kf + (size_t)b * (64 * 8 * 64 * 8);
  const bh16* vfb = Vf + (size_t)b * (64 * 8 * 512 * 8);
  const int cbase = cblk * 256 + w * 64;

#define KADDR(tile, ks) (kfb + (((size_t)(tile) * 8 + (ks) * 2 + hi) * 64 + jhalf * 32 + l31) * 8)
#define VADDR(tile, ks, ct) (vfb + (((size_t)(tile) * 8 + (ks) * 2 + hi) * 512 + cbase + (ct) * 32 + l31) * 8)

  f32x16 acc[2][2];
#pragma unroll
  for (int mt = 0; mt < 2; mt++)
#pragma unroll
    for (int ct = 0; ct < 2; ct++)
#pragma unroll
      for (int r = 0; r < 16; r++) acc[mt][ct][r] = 0.0f;
  float4 lsacc;
  lsacc.x = 0.0f; lsacc.y = 0.0f; lsacc.z = 0.0f; lsacc.w = 0.0f;

  // pipeline registers (single-buffered, reload-after-last-use)
  bf16x8 kf_nxt[4];       // K(it+1) at top of iter it
  bf16x8 vf_use[4][2];    // V(it-1) at top of iter it
  f32x16 s1;              // raw S(it)
  {
    bf16x8 k0[4];
#pragma unroll
    for (int ks = 0; ks < 4; ks++) {
      k0[ks] = *(const bf16x8*)KADDR(0, ks);
#pragma unroll
      for (int ct = 0; ct < 2; ct++) vf_use[ks][ct] = *(const bf16x8*)VADDR(0, ks, ct);
    }
#pragma unroll
    for (int ks = 0; ks < 4; ks++) kf_nxt[ks] = *(const bf16x8*)KADDR(1, ks);
#pragma unroll
    for (int r = 0; r < 16; r++) s1[r] = 0.0f;
#pragma unroll
    for (int ks = 0; ks < 4; ks++)
      s1 = __builtin_amdgcn_mfma_f32_32x32x16_bf16(k0[ks], qf[ks], s1, 0, 0, 0);
  }

  for (int it = 0; it < 64; it++) {
    // G1 for it+1 (result for next iteration; garbage at it=63, unused)
    f32x16 s1n;
#pragma unroll
    for (int r = 0; r < 16; r++) s1n[r] = 0.0f;
#pragma unroll
    for (int ks = 0; ks < 4; ks++)
      s1n = __builtin_amdgcn_mfma_f32_32x32x16_bf16(kf_nxt[ks], qf[ks], s1n, 0, 0, 0);
    // kf_nxt dead now -> reload K(it+2) immediately (cover = rest of body + barrier).
    // Unclamped: it=62/63 read past Kf into allocated xTb; result only reaches the
    // discarded final s1n.
    {
#pragma unroll
      for (int ks = 0; ks < 4; ks++) kf_nxt[ks] = *(const bf16x8*)KADDR(it + 2, ks);
    }

    const bh16* ps = Ps[(it + 1) & 1];  // == (it-1)&1
    bh16* psw = Ps[it & 1];
    if (it) {
      // G2(it-1) [MFMA] interleaved with exp/pack(it) [VALU] -- independent
#pragma unroll
      for (int ks = 0; ks < 4; ks++) {
        bf16x8 pf0 = *(const bf16x8*)&ps[(size_t)((ks * 2 + hi) * 64 + l31) * 8];
        bf16x8 pf1 = *(const bf16x8*)&ps[(size_t)((ks * 2 + hi) * 64 + 32 + l31) * 8];
        acc[0][0] = __builtin_amdgcn_mfma_f32_32x32x16_bf16(pf0, vf_use[ks][0], acc[0][0], 0, 0, 0);
        acc[0][1] = __builtin_amdgcn_mfma_f32_32x32x16_bf16(pf0, vf_use[ks][1], acc[0][1], 0, 0, 0);
        // one exp/pack group between MFMA clusters
        {
          union { bh16 h[4]; uint2 u2; } pk;
#pragma unroll
          for (int q = 0; q < 4; q++) {
            const float p = fexp2(s1[ks * 4 + q]);
            lsacc[q] += p;
            pk.h[q] = (bh16)p;
          }
          *(uint2*)(void*)&psw[(size_t)((jhalf * 4 + ks) * 64 + mhalf * 32 + l31) * 8 + hi * 4] = pk.u2;
        }
        acc[1][0] = __builtin_amdgcn_mfma_f32_32x32x16_bf16(pf1, vf_use[ks][0], acc[1][0], 0, 0, 0);
        acc[1][1] = __builtin_amdgcn_mfma_f32_32x32x16_bf16(pf1, vf_use[ks][1], acc[1][1], 0, 0, 0);
        // vf_use[ks] dead now -> reload V(it) for next iteration's G2 (~1-iter cover)
        vf_use[ks][0] = *(const bf16x8*)VADDR(it, ks, 0);
        vf_use[ks][1] = *(const bf16x8*)VADDR(it, ks, 1);
      }
    } else {
#pragma unroll
      for (int g = 0; g < 4; g++) {
        union { bh16 h[4]; uint2 u2; } pk;
#pragma unroll
        for (int q = 0; q < 4; q++) {
          const float p = fexp2(s1[g * 4 + q]);
          lsacc[q] += p;
          pk.h[q] = (bh16)p;
        }
        *(uint2*)(void*)&psw[(size_t)((jhalf * 4 + g) * 64 + mhalf * 32 + l31) * 8 + hi * 4] = pk.u2;
      }
      // vf_use keeps prologue-loaded V(0) for iter 1's G2
    }
    lbar();  // P(it) visible; K/V global loads stay in flight across the barrier
    s1 = s1n;
  }
  // final G2: P(63) x V(63)
  {
    const bh16* ps = Ps[1];
#pragma unroll
    for (int ks = 0; ks < 4; ks++) {
      bf16x8 pf0 = *(const bf16x8*)&ps[(size_t)((ks * 2 + hi) * 64 + l31) * 8];
      bf16x8 pf1 = *(const bf16x8*)&ps[(size_t)((ks * 2 + hi) * 64 + 32 + l31) * 8];
      acc[0][0] = __builtin_amdgcn_mfma_f32_32x32x16_bf16(pf0, vf_use[ks][0], acc[0][0], 0, 0, 0);
      acc[0][1] = __builtin_amdgcn_mfma_f32_32x32x16_bf16(pf0, vf_use[ks][1], acc[0][1], 0, 0, 0);
      acc[1][0] = __builtin_amdgcn_mfma_f32_32x32x16_bf16(pf1, vf_use[ks][0], acc[1][0], 0, 0, 0);
      acc[1][1] = __builtin_amdgcn_mfma_f32_32x32x16_bf16(pf1, vf_use[ks][1], acc[1][1], 0, 0, 0);
    }
  }
#undef KADDR
#undef VADDR

  // reduce row-sums: lanes (hi) within wave, then across jhalf wave pairs
  float lsum = (lsacc.x + lsacc.y) + (lsacc.z + lsacc.w);
  lsum += __shfl_xor(lsum, 32);
  if (hi == 0) lred[w][l31] = lsum;
  __syncthreads();
  if (t < 64) linvL[t] = 1.0f / (lred[(t >> 5) * 2][t & 31] + lred[(t >> 5) * 2 + 1][t & 31]);
  __syncthreads();

  // epilogue: normalize + residual, write pa[B][N][C] f16 + pooling partials
  float csum[2] = {0.0f, 0.0f};
  float cmax[2] = {-1e30f, -1e30f};
#pragma unroll
  for (int mt = 0; mt < 2; mt++) {
#pragma unroll
    for (int g = 0; g < 4; g++) {
      const int mloc = mt * 32 + g * 8 + hi * 4;
      const float4 lv = *(const float4*)&linvL[mloc];
#pragma unroll
      for (int ct = 0; ct < 2; ct++) {
        const int c = cbase + ct * 32 + l31;
        const float4 xv = *(const float4*)&x[(size_t)(b * CIN + c) * NPIX + mblk + mloc];
        float r0 = acc[mt][ct][g * 4 + 0] * lv.x + xv.x;
        float r1 = acc[mt][ct][g * 4 + 1] * lv.y + xv.y;
        float r2 = acc[mt][ct][g * 4 + 2] * lv.z + xv.z;
        float r3 = acc[mt][ct][g * 4 + 3] * lv.w + xv.w;
        csum[ct] += (r0 + r1) + (r2 + r3);
        cmax[ct] = fmaxf(cmax[ct], fmaxf(fmaxf(r0, r1), fmaxf(r2, r3)));
        fh16* pd = pa + ((size_t)(b * NPIX) + mblk + mloc) * CIN + c;
        pd[0 * CIN] = (fh16)r0;
        pd[1 * CIN] = (fh16)r1;
        pd[2 * CIN] = (fh16)r2;
        pd[3 * CIN] = (fh16)r3;
      }
    }
  }
  // combine hi halves (each holds 32 of the 64 pixels for the same c)
#pragma unroll
  for (int ct = 0; ct < 2; ct++) {
    csum[ct] += __shfl_xor(csum[ct], 32);
    cmax[ct] = fmaxf(cmax[ct], __shfl_xor(cmax[ct], 32));
  }
  if (hi == 0) {
    const int mb = mblk >> 6;
#pragma unroll
    for (int ct = 0; ct < 2; ct++) {
      const int c = cbase + ct * 32 + l31;
      psum[((size_t)b * 64 + mb) * CIN + c] = csum[ct];
      pmax[((size_t)b * 64 + mb) * CIN + c] = cmax[ct];
    }
  }
}

// ---------- channel-attention MLP (with fused partial-pool reduce) -> sigmoid scale ----------
// Layer-1 split 2 threads/dot (256 MACs each + shfl combine) -- halves the serial chain.
__global__ __launch_bounds__(256) void mlp2_k(const float* __restrict__ psum,
                                              const float* __restrict__ pmax,
                                              const float* __restrict__ w1,
                                              const float* __restrict__ w2,
                                              float* __restrict__ scale) {
  const int b = blockIdx.x;
  const int t = threadIdx.x;
  __shared__ float avg_l[CIN], max_l[CIN], hbuf[128];
#pragma unroll
  for (int h = 0; h < 2; h++) {
    const int c = t + h * 256;
    float s = 0.0f, m = -1e30f;
#pragma unroll
    for (int k = 0; k < 64; k++) {
      s += psum[((size_t)b * 64 + k) * CIN + c];
      m = fmaxf(m, pmax[((size_t)b * 64 + k) * CIN + c]);
    }
    avg_l[c] = s * (1.0f / 4096.0f);
    max_l[c] = m;
  }
  __syncthreads();
  {
    const int d = t >> 1;        // dot id 0..127 (0-63: avg, 64-127: max)
    const int hf = t & 1;        // half of the 512-long dot
    const float* src = (d < 64) ? avg_l : max_l;
    const int o = d & 63;
    float sacc = 0.0f;
    const int c0 = hf * 256;
    for (int c = c0; c < c0 + 256; c += 4) {
      const float4 wv = *(const float4*)&w1[o * CIN + c];
      sacc += wv.x * src[c] + wv.y * src[c + 1] + wv.z * src[c + 2] + wv.w * src[c + 3];
    }
    sacc += __shfl_xor(sacc, 1);
    if (hf == 0) hbuf[d] = fmaxf(sacc, 0.0f);
  }
  __syncthreads();
#pragma unroll
  for (int h = 0; h < 2; h++) {
    const int c = t + h * 256;
    float sacc = 0.0f;
#pragma unroll
    for (int k = 0; k < 64; k += 4) {
      const float4 wv = *(const float4*)&w2[c * 64 + k];
      sacc += wv.x * (hbuf[k] + hbuf[64 + k]) + wv.y * (hbuf[k + 1] + hbuf[64 + k + 1]) +
              wv.z * (hbuf[k + 2] + hbuf[64 + k + 2]) + wv.w * (hbuf[k + 3] + hbuf[64 + k + 3]);
    }
    scale[b * CIN + c] = 1.0f / (1.0f + __expf(-sacc));
  }
}

// ---------- pack pa[B][N][C] f16 * scale -> f16 padded pixel-major [B][66*66][512] ----------
// Same inner (channel) layout on both sides: pure coalesced row copy with per-ch scale.
__global__ __launch_bounds__(256) void pack_k(const fh16* __restrict__ pa,
                                              const float* __restrict__ scl,
                                              fh16* __restrict__ pab) {
  const int b = blockIdx.y;
  const int n0 = blockIdx.x * 8;
  const int t = threadIdx.x;
  __shared__ float sc[CIN];
#pragma unroll
  for (int h = 0; h < 2; h++) sc[t + h * 256] = scl[b * CIN + t + h * 256];
  __syncthreads();
  const int c2 = t * 2;
  const float s0 = sc[c2], s1 = sc[c2 + 1];
#pragma unroll
  for (int j = 0; j < 8; j++) {
    const int n = n0 + j;
    const int pp = ((n >> 6) + 1) * 66 + (n & 63) + 1;
    union { fh16 h[2]; unsigned int u; } v, o;
    v.u = *(const unsigned int*)(pa + ((size_t)b * NPIX + n) * CIN + c2);
    o.h[0] = (fh16)((float)v.h[0] * s0);
    o.h[1] = (fh16)((float)v.h[1] * s1);
    *(unsigned int*)(void*)(pab + ((size_t)b * PPIX + pp) * CIN + c2) = o.u;
  }
}

// ---------- zero the SAME-padding borders of pab (interior written by pack_k) ----------
// 260 border pixels per image: row0 (66), row65 (66), col0 rows1-64 (64), col65 rows1-64 (64)
__global__ __launch_bounds__(256) void bzero_k(fh16* __restrict__ pab) {
  const int t = threadIdx.x;
  const int p = blockIdx.x * 4 + (t >> 6);  // 0..259
  const int b = blockIdx.y;
  int pp;
  if (p < 66) pp = p;
  else if (p < 132) pp = 65 * 66 + (p - 66);
  else if (p < 196) pp = (p - 131) * 66;
  else pp = (p - 195) * 66 + 65;
  uint4 z = {0u, 0u, 0u, 0u};
  *(uint4*)(void*)(pab + ((size_t)b * PPIX + pp) * CIN + (t & 63) * 8) = z;
}

// ---------- repack conv weights -> f16 [oblk8][chunk32][tap9][chalf2][o32][8] ----------
// 32-output blocks (conv now runs 2 blocks/CU); chalf-major keeps 16B-lane-stride LDS reads.
__global__ __launch_bounds__(256) void wpack_k(const float* __restrict__ cw,
                                               fh16* __restrict__ wp) {
  const int slot = blockIdx.x * 256 + threadIdx.x;  // one 8-f16 group
  const int oblk = slot / 18432;        // 18432 = 32*9*2*32 groups per 32-out block
  const int r1 = slot - oblk * 18432;
  const int chunk = r1 / 576;           // 576 = 9*2*32
  const int r2 = r1 - chunk * 576;
  const int tap = r2 >> 6;
  const int r3 = r2 & 63;
  const int h = r3 >> 5;
  const int o = r3 & 31;
  const size_t sbase = (size_t)(oblk * 32 + o) * 4608 + (size_t)(chunk * 16 + h * 8) * 9 + tap;
  union { fh16 h8[8]; uint4 u4; } pk;
#pragma unroll
  for (int i = 0; i < 8; i++) pk.h8[i] = (fh16)cw[sbase + (size_t)i * 9];
  *(uint4*)(void*)(wp + (size_t)slot * 8) = pk.u4;
}

// ---------- implicit-GEMM 3x3 conv via f16 MFMA + BN + ReLU ----------
// 32 output channels/block (grid 512 -> 2 blocks/CU, 2 waves/SIMD: round-6 theory --
// the old 256-block config was 1 wave/SIMD with every latency fully exposed).
// Xs layout [batch13][chalf2][row32][8], Ws layout [tap9][chalf2][o32][8]:
// all ds_read_b128 at 16B lane stride.
__global__ __launch_bounds__(256) void conv_mfma_k(const fh16* __restrict__ pab,
                                                   const fh16* __restrict__ wp,
                                                   const float* __restrict__ gamma,
                                                   const float* __restrict__ beta,
                                                   const float* __restrict__ mean,
                                                   const float* __restrict__ var,
                                                   float* __restrict__ out) {
  const int y0 = blockIdx.x * 4;
  const int oblk = blockIdx.y;          // 0..7, 32 outputs each
  const int b = blockIdx.z;
  const int t = threadIdx.x;
  const int w = t >> 6, lane = t & 63, l31 = lane & 31, hi = lane >> 5;
  __shared__ __align__(16) fh16 Xs[2][416 * 16];
  __shared__ __align__(16) fh16 Ws[2][9 * 2 * 32 * 8];   // 4608 per buf
  __shared__ float sb[32], bb[32];
  if (t < 32) {
    const int o = oblk * 32 + t;
    const float inv = rsqrtf(var[o] + 1e-5f);
    const float sc = inv * gamma[o];
    sb[t] = sc;
    bb[t] = beta[o] - mean[o] * sc;
  }
  f32x16 o00, o01;
#pragma unroll
  for (int r = 0; r < 16; r++) { o00[r] = 0.0f; o01[r] = 0.0f; }

  // lane -> (row-in-batch = lane&31, chalf = lane>>5): LDS dest is linear, so the
  // [batch][chalf][row][8] layout is created purely by the per-lane GLOBAL address.
  const fh16* xbase = pab + ((size_t)b * PPIX + y0 * 66) * CIN + (size_t)l31 * CIN + hi * 8;
  const fh16* wbase = wp + (size_t)oblk * 147456 + lane * 8;

#define STAGE(chunk, buf)                                                        \
  {                                                                              \
    const fh16* xs = xbase + (chunk) * 16;                                       \
    for (int i = w; i < 13; i += 4)                                              \
      glds16(xs + (size_t)i * 32 * CIN, &Xs[buf][i * 512]);                      \
    const fh16* wsrc = wbase + (size_t)(chunk) * 4608;                           \
    for (int i = w; i < 9; i += 4)                                               \
      glds16(wsrc + (size_t)i * 512, &Ws[buf][i * 512]);                         \
  }

  STAGE(0, 0);
  __syncthreads();
  for (int chunk = 0; chunk < 32; chunk++) {
    if (chunk < 31) STAGE(chunk + 1, (chunk + 1) & 1);
    const fh16* xs = Xs[chunk & 1];
    const fh16* ws = Ws[chunk & 1];
#pragma unroll
    for (int tap = 0; tap < 9; tap++) {
      const int ky = tap / 3, kx = tap - ky * 3;
      const f16x8 a0 = *(const f16x8*)&ws[tap * 512 + hi * 256 + l31 * 8];
      const int row0 = (w + ky) * 66 + l31 + kx;
      const int row1 = row0 + 32;
      const f16x8 b0 = *(const f16x8*)&xs[(row0 >> 5) * 512 + hi * 256 + (row0 & 31) * 8];
      const f16x8 b1 = *(const f16x8*)&xs[(row1 >> 5) * 512 + hi * 256 + (row1 & 31) * 8];
      o00 = __builtin_amdgcn_mfma_f32_32x32x16_f16(a0, b0, o00, 0, 0, 0);
      o01 = __builtin_amdgcn_mfma_f32_32x32x16_f16(a0, b1, o01, 0, 0, 0);
    }
    __syncthreads();
  }
#undef STAGE

  const f32x16* accs[2] = {&o00, &o01};
#pragma unroll
  for (int nt = 0; nt < 2; nt++) {
    const f32x16& A = *accs[nt];
#pragma unroll
    for (int r = 0; r < 16; r++) {
      const int cl = (r & 3) + 8 * (r >> 2) + 4 * hi;
      const int pix = nt * 32 + l31;
      const float y = A[r] * sb[cl] + bb[cl];
      out[((size_t)(b * COUT + oblk * 32 + cl)) * NPIX + (y0 + w) * 64 + pix] = fmaxf(y, 0.0f);
    }
  }
}

extern "C" void kernel_launch(void* const* d_in, const int* in_sizes, int n_in,
                              void* d_out, int out_size, void* d_ws, size_t ws_size,
                              hipStream_t stream) {
  (void)in_sizes; (void)n_in; (void)out_size; (void)ws_size;
  const float* x        = (const float*)d_in[0];
  const float* wq       = (const float*)d_in[1];
  const float* bq       = (const float*)d_in[2];
  const float* wk       = (const float*)d_in[3];
  const float* bk       = (const float*)d_in[4];
  const float* wv       = (const float*)d_in[5];
  const float* bv       = (const float*)d_in[6];
  const float* ca_w1    = (const float*)d_in[7];
  const float* ca_w2    = (const float*)d_in[8];
  const float* conv_w   = (const float*)d_in[9];
  const float* bn_gamma = (const float*)d_in[10];
  const float* bn_beta  = (const float*)d_in[11];
  const float* bn_mean  = (const float*)d_in[12];
  const float* bn_var   = (const float*)d_in[13];
  float* out = (float*)d_out;

  float* ws = (float*)d_ws;
  fh16*  pa      = (fh16*)ws;                   // [B][N][C] f16 (16.8 MB)
  float* psum    = ws + 4194304;                // [B][64][C] fp32 partial sums (512 KB)
  float* pmax    = ws + 4325376;                // [B][64][C] fp32 partial maxes (512 KB)
  bh16*  Vf      = (bh16*)(ws + 8388608);       // [B][64][8][512][8] bf16 (aliased by wpck later)
  fh16*  wpck    = (fh16*)(ws + 8388608);       // conv weights f16 (after attn)
  bh16*  Qb      = (bh16*)(ws + 12582912);      // [B*N][64] bf16
  bh16*  Kf      = (bh16*)(ws + 13107200);      // [B][64][8][64][8] bf16
  bh16*  xTb     = (bh16*)(ws + 13631488);      // [B][N][C] bf16 (aliased by pab later)
  fh16*  pab     = (fh16*)(ws + 13631488);      // [B][4356][512] f16 + pad
  bh16*  Wqk     = (bh16*)(ws + 17825792);      // [128][512] bf16
  bh16*  wvb     = (bh16*)(ws + 17858560);      // [512][512] bf16
  float* bias128 = ws + 17989632;
  float* scl     = ws + 18104320;

  wcast_k<<<dim3(1280, 1, 1), 256, 0, stream>>>(wq, wk, wv, bq, bk, Wqk, wvb, bias128);
  transpose_bf_k<<<dim3(NPIX / 64, CIN / 64, NB), 256, 0, stream>>>(x, xTb);
  qk_proj_k<<<dim3(256, 1, 1), 256, 0, stream>>>(xTb, Wqk, bias128, Qb, Kf);
  v_proj_k<<<dim3(16, 8, NB), 256, 0, stream>>>(xTb, wvb, bv, Vf);
  attn1p_k<<<dim3(2, 64, NB), 256, 0, stream>>>(Qb, Kf, Vf, x, pa, psum, pmax);
  // xTb dead now: zero only the conv SAME-padding borders (pack_k writes all interior;
  // staging over-reads past pab land in allocated pad and are never consumed)
  bzero_k<<<dim3(65, NB, 1), 256, 0, stream>>>(pab);
  mlp2_k<<<dim3(NB, 1, 1), 256, 0, stream>>>(psum, pmax, ca_w1, ca_w2, scl);
  pack_k<<<dim3(NPIX / 8, NB, 1), 256, 0, stream>>>(pa, scl, pab);
  wpack_k<<<dim3(576, 1, 1), 256, 0, stream>>>(conv_w, wpck);  // Vf dead now
  conv_mfma_k<<<dim3(16, 8, NB), 256, 0, stream>>>(pab, wpck, bn_gamma, bn_beta,
                                                   bn_mean, bn_var, out);
}